// Round 1
// baseline (537.668 us; speedup 1.0000x reference)
//
#include <hip/hip_runtime.h>

// ---------------------------------------------------------------------------
// Cosine-attention transformer block, MI355X gfx950.
// Pipeline:
//   1. cast x, Wq..W3 -> bf16
//   2. Q = x@Wq^T+bq (f32), K = x@Wk^T+bk (f32), V = x@Wv^T+bv (bf16)
//   3. Qn,Kn = L2-normalize rows -> bf16 ; Vt = V^T (bf16, per batch)
//   4. sim = Qn@Kn^T (f32, per batch)      [NT GEMM]
//   5. P = softmax(sim) -> bf16
//   6. attnout = P@Vt^T (bf16, per batch)  [NT GEMM vs V^T]
//   7. h1 = relu(attnout@W1^T+b1) bf16 ; h2 = relu(h1@W2^T+b2) bf16
//   8. out = h2@W3^T+b3 -> f32 d_out
//
// All GEMMs are NT (A [M,K] row-major, B stored [N,K]) -> both K-contiguous.
// GEMM: m97 structure — 128x128 tile, 4 waves (2x2 of 64x64), BK=32,
// mfma_f32_16x16x32_bf16, global_load_lds width 16, 2 barriers/K-step.
//
// Workspace layout (168 MiB, lifetime-aliased):
//   [0,   64Mi): Qf32+Kf32  ->  sim f32  ->  h2 bf16
//   [64,  96Mi): x_bf16 + V_bf16  ->  P bf16
//   [96, 120Mi): weights bf16 (Wq,Wk,Wv,W1: 2Mi each; W2: 8Mi; W3: 8Mi)
//   [120,168Mi): Qn, Kn, Vt bf16 (16Mi each); attnout aliases Qn, h1 aliases Kn
// ---------------------------------------------------------------------------

using u16 = unsigned short;
using bf16x8 = __attribute__((ext_vector_type(8))) __bf16;
using f32x4  = __attribute__((ext_vector_type(4))) float;

__device__ __forceinline__ u16 f2bf(float f) {
  unsigned u = __float_as_uint(f);
  unsigned r = (u + 0x7FFFu + ((u >> 16) & 1u)) >> 16;
  return (u16)r;
}

// ---------------- fp32 -> bf16 cast (vectorized x4) ----------------
__global__ __launch_bounds__(256) void cast_bf16_kernel(
    const float* __restrict__ in, u16* __restrict__ out, int n4) {
  int i = blockIdx.x * 256 + threadIdx.x;
  if (i < n4) {
    float4 v = reinterpret_cast<const float4*>(in)[i];
    ushort4 o;
    o.x = f2bf(v.x); o.y = f2bf(v.y); o.z = f2bf(v.z); o.w = f2bf(v.w);
    reinterpret_cast<ushort4*>(out)[i] = o;
  }
}

// ---------------- row L2-normalize: f32 [rows][1024] -> bf16 ----------------
__global__ __launch_bounds__(256) void l2norm_kernel(
    const float* __restrict__ in, u16* __restrict__ out) {
  __shared__ float red[4];
  long row = blockIdx.x;
  const int tid = threadIdx.x, lane = tid & 63, wave = tid >> 6;
  const float* p = in + row * 1024;
  float4 x = *reinterpret_cast<const float4*>(p + tid * 4);
  float ss = x.x * x.x + x.y * x.y + x.z * x.z + x.w * x.w;
#pragma unroll
  for (int o = 32; o; o >>= 1) ss += __shfl_xor(ss, o);
  if (lane == 0) red[wave] = ss;
  __syncthreads();
  ss = red[0] + red[1] + red[2] + red[3];
  float s = 1.0f / fmaxf(sqrtf(ss), 1e-12f);
  ushort4 o;
  o.x = f2bf(x.x * s); o.y = f2bf(x.y * s); o.z = f2bf(x.z * s); o.w = f2bf(x.w * s);
  *reinterpret_cast<ushort4*>(out + row * 1024 + tid * 4) = o;
}

// ---------------- bf16 transpose: in [rows][cols] -> out [cols][rows] -------
__global__ void transpose_kernel(const u16* __restrict__ in, u16* __restrict__ out,
                                 int rows, int cols) {
  __shared__ u16 t[32][33];
  const int c0 = blockIdx.x * 32, r0 = blockIdx.y * 32;
  const long off = (long)blockIdx.z * rows * cols;
  const u16* ib = in + off;
  u16* ob = out + off;
  const int tx = threadIdx.x, ty = threadIdx.y;  // (32, 8)
#pragma unroll
  for (int j = 0; j < 4; ++j)
    t[ty + j * 8][tx] = ib[(long)(r0 + ty + j * 8) * cols + c0 + tx];
  __syncthreads();
#pragma unroll
  for (int j = 0; j < 4; ++j)
    ob[(long)(c0 + ty + j * 8) * rows + r0 + tx] = t[tx][ty + j * 8];
}

// ---------------- row softmax: f32 [rows][2048] -> bf16 ----------------
__global__ __launch_bounds__(256) void softmax_kernel(
    const float* __restrict__ in, u16* __restrict__ out) {
  __shared__ float red[4];
  long row = blockIdx.x;
  const int tid = threadIdx.x, lane = tid & 63, wave = tid >> 6;
  const float* p = in + row * 2048;
  float v[8];
  float4 a = *reinterpret_cast<const float4*>(p + tid * 8);
  float4 b = *reinterpret_cast<const float4*>(p + tid * 8 + 4);
  v[0] = a.x; v[1] = a.y; v[2] = a.z; v[3] = a.w;
  v[4] = b.x; v[5] = b.y; v[6] = b.z; v[7] = b.w;
  float m = v[0];
#pragma unroll
  for (int i = 1; i < 8; ++i) m = fmaxf(m, v[i]);
#pragma unroll
  for (int o = 32; o; o >>= 1) m = fmaxf(m, __shfl_xor(m, o));
  if (lane == 0) red[wave] = m;
  __syncthreads();
  m = fmaxf(fmaxf(red[0], red[1]), fmaxf(red[2], red[3]));
  float s = 0.0f;
#pragma unroll
  for (int i = 0; i < 8; ++i) { v[i] = __expf(v[i] - m); s += v[i]; }
#pragma unroll
  for (int o = 32; o; o >>= 1) s += __shfl_xor(s, o);
  __syncthreads();
  if (lane == 0) red[wave] = s;
  __syncthreads();
  s = red[0] + red[1] + red[2] + red[3];
  float inv = 1.0f / s;
  ushort4 o0, o1;
  o0.x = f2bf(v[0] * inv); o0.y = f2bf(v[1] * inv);
  o0.z = f2bf(v[2] * inv); o0.w = f2bf(v[3] * inv);
  o1.x = f2bf(v[4] * inv); o1.y = f2bf(v[5] * inv);
  o1.z = f2bf(v[6] * inv); o1.w = f2bf(v[7] * inv);
  *reinterpret_cast<ushort4*>(out + row * 2048 + tid * 8) = o0;
  *reinterpret_cast<ushort4*>(out + row * 2048 + tid * 8 + 4) = o1;
}

// ---------------- bf16 NT GEMM, m97 structure ----------------
// C[m,n] = sum_k A[m,k]*B[n,k] (+bias[n]) (+relu). M,N mult of 128; K mult of 32.
template <bool BF16OUT>
__global__ __launch_bounds__(256) void gemm_nt_kernel(
    const u16* __restrict__ A, const u16* __restrict__ Bw,
    const float* __restrict__ bias, void* __restrict__ Cout,
    int M, int N, int K, long batchA, long batchB, long batchC, int relu) {
  __shared__ u16 lA[4096];  // [128][32] bf16
  __shared__ u16 lB[4096];
  const int tid = threadIdx.x;
  const int wave = tid >> 6, lane = tid & 63;
  const int wr = wave >> 1, wc = wave & 1;  // wave 2x2 -> 64x64 each
  const u16* Ab = A + blockIdx.z * batchA + (long)blockIdx.y * 128 * K;
  const u16* Bb = Bw + blockIdx.z * batchB + (long)blockIdx.x * 128 * K;

  f32x4 acc[4][4] = {};
  const int ch0 = wave * 2;          // each wave stages 2 chunks of 1KB per tile
  const int srow = lane >> 2;        // row within 16-row chunk
  const int scol = (lane & 3) * 8;   // bf16 col offset

  for (int k0 = 0; k0 < K; k0 += 32) {
#pragma unroll
    for (int i = 0; i < 2; ++i) {
      const int ch = ch0 + i;
      __builtin_amdgcn_global_load_lds(
          (const __attribute__((address_space(1))) void*)(Ab + (long)(ch * 16 + srow) * K + k0 + scol),
          (__attribute__((address_space(3))) void*)&lA[ch * 512], 16, 0, 0);
      __builtin_amdgcn_global_load_lds(
          (const __attribute__((address_space(1))) void*)(Bb + (long)(ch * 16 + srow) * K + k0 + scol),
          (__attribute__((address_space(3))) void*)&lB[ch * 512], 16, 0, 0);
    }
    __syncthreads();
    const int fr = lane & 15, koff = (lane >> 4) * 8;
    bf16x8 af[4], bfr[4];
#pragma unroll
    for (int m = 0; m < 4; ++m)
      af[m] = *reinterpret_cast<const bf16x8*>(&lA[(wr * 64 + m * 16 + fr) * 32 + koff]);
#pragma unroll
    for (int n = 0; n < 4; ++n)
      bfr[n] = *reinterpret_cast<const bf16x8*>(&lB[(wc * 64 + n * 16 + fr) * 32 + koff]);
#pragma unroll
    for (int m = 0; m < 4; ++m)
#pragma unroll
      for (int n = 0; n < 4; ++n)
        acc[m][n] = __builtin_amdgcn_mfma_f32_16x16x32_bf16(af[m], bfr[n], acc[m][n], 0, 0, 0);
    __syncthreads();
  }

  // Epilogue. C/D layout (m89-verified): col = lane&15, row = (lane>>4)*4 + j.
  const long cbase = blockIdx.z * batchC;
  const int row0 = blockIdx.y * 128 + wr * 64 + ((lane >> 4) << 2);
  const int col0 = blockIdx.x * 128 + wc * 64 + (lane & 15);
#pragma unroll
  for (int n = 0; n < 4; ++n) {
    const int c = col0 + n * 16;
    const float bb = bias ? bias[c] : 0.0f;
#pragma unroll
    for (int m = 0; m < 4; ++m) {
#pragma unroll
      for (int j = 0; j < 4; ++j) {
        const int r = row0 + m * 16 + j;
        float v = acc[m][n][j] + bb;
        if (relu) v = fmaxf(v, 0.0f);
        if (BF16OUT)
          ((u16*)Cout)[cbase + (long)r * N + c] = f2bf(v);
        else
          ((float*)Cout)[cbase + (long)r * N + c] = v;
      }
    }
  }
}

// ---------------------------------------------------------------------------
extern "C" void kernel_launch(void* const* d_in, const int* in_sizes, int n_in,
                              void* d_out, int out_size, void* d_ws, size_t ws_size,
                              hipStream_t stream) {
  (void)in_sizes; (void)n_in; (void)out_size; (void)ws_size;
  const float* x  = (const float*)d_in[0];
  const float* Wq = (const float*)d_in[1];
  const float* bq = (const float*)d_in[2];
  const float* Wk = (const float*)d_in[3];
  const float* bk = (const float*)d_in[4];
  const float* Wv = (const float*)d_in[5];
  const float* bv = (const float*)d_in[6];
  const float* W1 = (const float*)d_in[7];
  const float* b1 = (const float*)d_in[8];
  const float* W2 = (const float*)d_in[9];
  const float* b2 = (const float*)d_in[10];
  const float* W3 = (const float*)d_in[11];
  const float* b3 = (const float*)d_in[12];

  char* ws = (char*)d_ws;
  const size_t MB = 1u << 20;
  // region 0: 64 MiB
  float* Qf   = (float*)(ws + 0);
  float* Kf   = Qf + (size_t)8192 * 1024;
  float* simf = (float*)(ws + 0);
  u16*   h2   = (u16*)(ws + 0);
  // region 1: 32 MiB
  u16* xbf = (u16*)(ws + 64 * MB);
  u16* Vbf = xbf + (size_t)8192 * 1024;
  u16* P   = (u16*)(ws + 64 * MB);
  // region 2: 24 MiB (weights, persistent)
  u16* Wq_b = (u16*)(ws + 96 * MB);
  u16* Wk_b = Wq_b + 1048576;
  u16* Wv_b = Wk_b + 1048576;
  u16* W1_b = Wv_b + 1048576;
  u16* W2_b = W1_b + 1048576;
  u16* W3_b = W2_b + 4194304;
  // region 3: 48 MiB
  u16* Qn = (u16*)(ws + 120 * MB);
  u16* Kn = Qn + 8388608;
  u16* Vt = Kn + 8388608;
  u16* attnout = Qn;  // Qn dead after sim GEMM
  u16* h1      = Kn;  // Kn dead after sim GEMM

  // 1. casts
  cast_bf16_kernel<<<8192, 256, 0, stream>>>(x,  xbf,  2097152);
  cast_bf16_kernel<<<1024, 256, 0, stream>>>(Wq, Wq_b, 262144);
  cast_bf16_kernel<<<1024, 256, 0, stream>>>(Wk, Wk_b, 262144);
  cast_bf16_kernel<<<1024, 256, 0, stream>>>(Wv, Wv_b, 262144);
  cast_bf16_kernel<<<1024, 256, 0, stream>>>(W1, W1_b, 262144);
  cast_bf16_kernel<<<4096, 256, 0, stream>>>(W2, W2_b, 1048576);
  cast_bf16_kernel<<<4096, 256, 0, stream>>>(W3, W3_b, 1048576);

  dim3 blk(256);
  // 2. QKV projections
  gemm_nt_kernel<false><<<dim3(8, 64, 1), blk, 0, stream>>>(xbf, Wq_b, bq, Qf, 8192, 1024, 1024, 0, 0, 0, 0);
  gemm_nt_kernel<false><<<dim3(8, 64, 1), blk, 0, stream>>>(xbf, Wk_b, bk, Kf, 8192, 1024, 1024, 0, 0, 0, 0);
  gemm_nt_kernel<true ><<<dim3(8, 64, 1), blk, 0, stream>>>(xbf, Wv_b, bv, Vbf, 8192, 1024, 1024, 0, 0, 0, 0);
  // 3. normalize + transpose
  l2norm_kernel<<<8192, 256, 0, stream>>>(Qf, Qn);
  l2norm_kernel<<<8192, 256, 0, stream>>>(Kf, Kn);
  transpose_kernel<<<dim3(32, 64, 4), dim3(32, 8), 0, stream>>>(Vbf, Vt, 2048, 1024);
  // 4. sim = Qn @ Kn^T  (per batch)
  gemm_nt_kernel<false><<<dim3(16, 16, 4), blk, 0, stream>>>(Qn, Kn, nullptr, simf,
      2048, 2048, 1024, 2097152L, 2097152L, 4194304L, 0);
  // 5. softmax
  softmax_kernel<<<8192, 256, 0, stream>>>(simf, P);
  // 6. attnout = P @ V  (NT vs Vt)
  gemm_nt_kernel<true><<<dim3(8, 16, 4), blk, 0, stream>>>(P, Vt, nullptr, attnout,
      2048, 1024, 2048, 4194304L, 2097152L, 2097152L, 0);
  // 7. MLP
  gemm_nt_kernel<true ><<<dim3(8,  64, 1), blk, 0, stream>>>(attnout, W1_b, b1, h1, 8192, 1024, 1024, 0, 0, 0, 1);
  gemm_nt_kernel<true ><<<dim3(32, 64, 1), blk, 0, stream>>>(h1, W2_b, b2, h2, 8192, 4096, 1024, 0, 0, 0, 1);
  gemm_nt_kernel<false><<<dim3(8,  64, 1), blk, 0, stream>>>(h2, W3_b, b3, (float*)d_out, 8192, 1024, 4096, 0, 0, 0, 0);
}

// Round 2
// 484.630 us; speedup vs baseline: 1.1094x; 1.1094x over previous
//
#include <hip/hip_runtime.h>

// ---------------------------------------------------------------------------
// Cosine-attention transformer block, MI355X gfx950.  Round 2: 8-phase GEMM.
//
// GEMM template (T2+T3+T4+T5 combo, schedule safety derived below):
//   BN=256, BK=64, 512 threads = 8 waves (2M x 4N).  BM in {128,256}.
//   Per-wave C: (BM/2) rows x 64 cols, with rows/cols INTERLEAVED across
//   tile halves: qm half selects A-half, qn half selects B-half, so
//   phase (qm,qn) = ph in {(0,0),(1,0),(0,1),(1,1)} reads exactly one
//   A-half and one B-half.
//   LDS: A[2][BM][64], B[2][256][64] bf16, 128B rows, XOR swizzle
//   granule^=row&7 (16B granules) -> ds_read 2-way bank alias (free).
//   Staged via global_load_lds w=16 with pre-swizzled per-lane source.
//
//   Schedule per K-tile t (4 phases), staging K-tile t+1 into other buffer:
//     ph0: read Ah0xBh0 frags; stage Ah0(t+1)
//     ph1: read Ah1xBh0;       stage Ah1(t+1); vmcnt(4|2) [Bh1(t) landed]
//     ph2: read Ah0xBh1;       stage Bh0(t+1)
//     ph3: read Ah1xBh1;       stage Bh1(t+1); vmcnt(2) [Ah0..Bh0(t+1) landed]
//   vmcnt counts (BM=256, 2 loads/half-tile/thread):
//     at ph3: outstanding = 8 (t+1); vmcnt(2) -> Ah0,Ah1,Bh0 done, Bh1 in flight
//     at ph1: outstanding = Bh1(t)=2 + Ah0,Ah1(t+2)=4; vmcnt(4) -> Bh1(t) done
//   (BM=128: 1 load per A half -> vmcnt(2) at both points.)
//   Buffer overwrite safety: staging t+1 targets the buffer whose tile (t-1)
//   was fully consumed before iteration t began (barrier-separated).
// ---------------------------------------------------------------------------

using u16 = unsigned short;
using bf16x8 = __attribute__((ext_vector_type(8))) __bf16;
using f32x4  = __attribute__((ext_vector_type(4))) float;

__device__ __forceinline__ u16 f2bf(float f) {
  unsigned u = __float_as_uint(f);
  unsigned r = (u + 0x7FFFu + ((u >> 16) & 1u)) >> 16;
  return (u16)r;
}

// ---------------- fp32 -> bf16 cast (vectorized x4) ----------------
__global__ __launch_bounds__(256) void cast_bf16_kernel(
    const float* __restrict__ in, u16* __restrict__ out, int n4) {
  int i = blockIdx.x * 256 + threadIdx.x;
  if (i < n4) {
    float4 v = reinterpret_cast<const float4*>(in)[i];
    ushort4 o;
    o.x = f2bf(v.x); o.y = f2bf(v.y); o.z = f2bf(v.z); o.w = f2bf(v.w);
    reinterpret_cast<ushort4*>(out)[i] = o;
  }
}

// ---------------- row L2-normalize: f32 [rows][1024] -> bf16 ----------------
__global__ __launch_bounds__(256) void l2norm_kernel(
    const float* __restrict__ in, u16* __restrict__ out) {
  __shared__ float red[4];
  long row = blockIdx.x;
  const int tid = threadIdx.x, lane = tid & 63, wave = tid >> 6;
  const float* p = in + row * 1024;
  float4 x = *reinterpret_cast<const float4*>(p + tid * 4);
  float ss = x.x * x.x + x.y * x.y + x.z * x.z + x.w * x.w;
#pragma unroll
  for (int o = 32; o; o >>= 1) ss += __shfl_xor(ss, o);
  if (lane == 0) red[wave] = ss;
  __syncthreads();
  ss = red[0] + red[1] + red[2] + red[3];
  float s = 1.0f / fmaxf(sqrtf(ss), 1e-12f);
  ushort4 o;
  o.x = f2bf(x.x * s); o.y = f2bf(x.y * s); o.z = f2bf(x.z * s); o.w = f2bf(x.w * s);
  *reinterpret_cast<ushort4*>(out + row * 1024 + tid * 4) = o;
}

// ---------------- bf16 transpose: in [rows][cols] -> out [cols][rows] -------
__global__ void transpose_kernel(const u16* __restrict__ in, u16* __restrict__ out,
                                 int rows, int cols) {
  __shared__ u16 t[32][33];
  const int c0 = blockIdx.x * 32, r0 = blockIdx.y * 32;
  const long off = (long)blockIdx.z * rows * cols;
  const u16* ib = in + off;
  u16* ob = out + off;
  const int tx = threadIdx.x, ty = threadIdx.y;  // (32, 8)
#pragma unroll
  for (int j = 0; j < 4; ++j)
    t[ty + j * 8][tx] = ib[(long)(r0 + ty + j * 8) * cols + c0 + tx];
  __syncthreads();
#pragma unroll
  for (int j = 0; j < 4; ++j)
    ob[(long)(c0 + ty + j * 8) * rows + r0 + tx] = t[tx][ty + j * 8];
}

// ---------------- row softmax: f32 [rows][2048] -> bf16 ----------------
__global__ __launch_bounds__(256) void softmax_kernel(
    const float* __restrict__ in, u16* __restrict__ out) {
  __shared__ float red[4];
  long row = blockIdx.x;
  const int tid = threadIdx.x, lane = tid & 63, wave = tid >> 6;
  const float* p = in + row * 2048;
  float v[8];
  float4 a = *reinterpret_cast<const float4*>(p + tid * 8);
  float4 b = *reinterpret_cast<const float4*>(p + tid * 8 + 4);
  v[0] = a.x; v[1] = a.y; v[2] = a.z; v[3] = a.w;
  v[4] = b.x; v[5] = b.y; v[6] = b.z; v[7] = b.w;
  float m = v[0];
#pragma unroll
  for (int i = 1; i < 8; ++i) m = fmaxf(m, v[i]);
#pragma unroll
  for (int o = 32; o; o >>= 1) m = fmaxf(m, __shfl_xor(m, o));
  if (lane == 0) red[wave] = m;
  __syncthreads();
  m = fmaxf(fmaxf(red[0], red[1]), fmaxf(red[2], red[3]));
  float s = 0.0f;
#pragma unroll
  for (int i = 0; i < 8; ++i) { v[i] = __expf(v[i] - m); s += v[i]; }
#pragma unroll
  for (int o = 32; o; o >>= 1) s += __shfl_xor(s, o);
  __syncthreads();
  if (lane == 0) red[wave] = s;
  __syncthreads();
  s = red[0] + red[1] + red[2] + red[3];
  float inv = 1.0f / s;
  ushort4 o0, o1;
  o0.x = f2bf(v[0] * inv); o0.y = f2bf(v[1] * inv);
  o0.z = f2bf(v[2] * inv); o0.w = f2bf(v[3] * inv);
  o1.x = f2bf(v[4] * inv); o1.y = f2bf(v[5] * inv);
  o1.z = f2bf(v[6] * inv); o1.w = f2bf(v[7] * inv);
  *reinterpret_cast<ushort4*>(out + row * 2048 + tid * 8) = o0;
  *reinterpret_cast<ushort4*>(out + row * 2048 + tid * 8 + 4) = o1;
}

// ---------------- 8-phase bf16 NT GEMM ----------------
// C[m,n] = sum_k A[m,k]*B[n,k] (+bias[n]) (+relu).
// Grid: (N/256, M/BM, batch), 512 threads. M%BM==0, N%256==0, K%64==0.
template <int BM, bool BF16OUT>
__global__ __launch_bounds__(512, 2) void gemm8p(
    const u16* __restrict__ A, const u16* __restrict__ Bw,
    const float* __restrict__ bias, void* __restrict__ Cout,
    int N, int K, long batchA, long batchB, long batchC, int relu) {
  constexpr int MF  = BM / 32;        // m-frags per wave (8 or 4)
  constexpr int ASZ = BM * 64;        // u16 per A buffer
  constexpr int BSZ = 256 * 64;
  constexpr int AR  = BM / 64;        // A stage rounds per K-tile (4 or 2)
  __shared__ u16 lds[2 * ASZ + 2 * BSZ];

  const int tid = threadIdx.x, wave = tid >> 6, lane = tid & 63;
  const int wr = wave >> 2, wc = wave & 3;
  const int fr = lane & 15, hi = lane >> 4;

  const long Abase = blockIdx.z * batchA + (long)blockIdx.y * BM * K;
  const long Bbase = blockIdx.z * batchB + (long)blockIdx.x * 256 * K;

  // ---- precomputed swizzled ds_read offsets (u16 units) ----
  int aoff[MF][2], boff[4][2];
#pragma unroll
  for (int m = 0; m < MF; ++m) {
    const int qm = m / (MF / 2), ml = m % (MF / 2);
    const int row = qm * (BM / 2) + wr * (BM / 4) + ml * 16 + fr;
#pragma unroll
    for (int ks = 0; ks < 2; ++ks) {
      const int gg = ks * 4 + hi;
      aoff[m][ks] = row * 64 + ((gg ^ (row & 7)) * 8);
    }
  }
#pragma unroll
  for (int n = 0; n < 4; ++n) {
    const int qn = n >> 1, nl = n & 1;
    const int row = qn * 128 + wc * 32 + nl * 16 + fr;
#pragma unroll
    for (int ks = 0; ks < 2; ++ks) {
      const int gg = ks * 4 + hi;
      boff[n][ks] = row * 64 + ((gg ^ (row & 7)) * 8);
    }
  }

  // ---- precomputed stage source offsets (pre-swizzled global, m173) ----
  // physical LDS byte p = r*8192 + tid*16 -> prow = r*64+wave*8+(lane>>3),
  // phys granule = lane&7, logical granule g = (lane&7) ^ (lane>>3).
  const int rA  = wave * 8 + (lane >> 3);
  const int g8  = (((lane & 7) ^ (lane >> 3)) * 8);
  long asrc[AR], bsrc[4];
#pragma unroll
  for (int r = 0; r < AR; ++r) asrc[r] = Abase + (long)(r * 64 + rA) * K + g8;
#pragma unroll
  for (int r = 0; r < 4; ++r) bsrc[r] = Bbase + (long)(r * 64 + rA) * K + g8;

#define STAGE_A(bufp, r, k0)                                                   \
  __builtin_amdgcn_global_load_lds(                                            \
      (const __attribute__((address_space(1))) void*)(A + asrc[r] + (k0)),     \
      (__attribute__((address_space(3))) void*)((bufp) + (r) * 4096 + wave * 512), \
      16, 0, 0)
#define STAGE_B(bufp, r, k0)                                                   \
  __builtin_amdgcn_global_load_lds(                                            \
      (const __attribute__((address_space(1))) void*)(Bw + bsrc[r] + (k0)),    \
      (__attribute__((address_space(3))) void*)((bufp) + (r) * 4096 + wave * 512), \
      16, 0, 0)

  // ---- prologue: stage K-tile 0 into buffer 0, drain, barrier ----
  {
    u16* a0 = lds;
    u16* b0 = lds + 2 * ASZ;
#pragma unroll
    for (int r = 0; r < AR; ++r) STAGE_A(a0, r, 0);
#pragma unroll
    for (int r = 0; r < 4; ++r) STAGE_B(b0, r, 0);
    asm volatile("s_waitcnt vmcnt(0)" ::: "memory");
    __builtin_amdgcn_s_barrier();
  }

  f32x4 acc[MF][4] = {};
  const int NT = K >> 6;

  for (int t = 0; t < NT; ++t) {
    const int cur = t & 1, nxt = cur ^ 1;
    const bool hasNext = (t + 1) < NT;
    const int k0n = (t + 1) << 6;
    u16* curA = lds + cur * ASZ;
    u16* curB = lds + 2 * ASZ + cur * BSZ;
    u16* nxtA = lds + nxt * ASZ;
    u16* nxtB = lds + 2 * ASZ + nxt * BSZ;

#pragma unroll
    for (int ph = 0; ph < 4; ++ph) {
      const int qm = ph & 1, qn = ph >> 1;
      // ds_read this phase's fragments
      bf16x8 af[MF / 2][2], bf[2][2];
#pragma unroll
      for (int mm = 0; mm < MF / 2; ++mm)
#pragma unroll
        for (int ks = 0; ks < 2; ++ks)
          af[mm][ks] = *reinterpret_cast<const bf16x8*>(
              &curA[aoff[qm * (MF / 2) + mm][ks]]);
#pragma unroll
      for (int nn = 0; nn < 2; ++nn)
#pragma unroll
        for (int ks = 0; ks < 2; ++ks)
          bf[nn][ks] = *reinterpret_cast<const bf16x8*>(
              &curB[boff[qn * 2 + nn][ks]]);
      // stage one half-tile of K-tile t+1
      if (hasNext) {
        if (ph == 0) {
#pragma unroll
          for (int r = 0; r < AR / 2; ++r) STAGE_A(nxtA, r, k0n);
        } else if (ph == 1) {
#pragma unroll
          for (int r = AR / 2; r < AR; ++r) STAGE_A(nxtA, r, k0n);
        } else if (ph == 2) {
          STAGE_B(nxtB, 0, k0n); STAGE_B(nxtB, 1, k0n);
        } else {
          STAGE_B(nxtB, 2, k0n); STAGE_B(nxtB, 3, k0n);
        }
      }
      __builtin_amdgcn_s_barrier();
      __builtin_amdgcn_s_setprio(1);
#pragma unroll
      for (int ks = 0; ks < 2; ++ks)
#pragma unroll
        for (int mm = 0; mm < MF / 2; ++mm)
#pragma unroll
          for (int nn = 0; nn < 2; ++nn)
            acc[qm * (MF / 2) + mm][qn * 2 + nn] =
                __builtin_amdgcn_mfma_f32_16x16x32_bf16(
                    af[mm][ks], bf[nn][ks],
                    acc[qm * (MF / 2) + mm][qn * 2 + nn], 0, 0, 0);
      __builtin_amdgcn_s_setprio(0);
      // counted vmcnt (T4): see schedule derivation at file top
      if (ph == 1) {
        if (hasNext) {
          if (BM == 256) asm volatile("s_waitcnt vmcnt(4)" ::: "memory");
          else           asm volatile("s_waitcnt vmcnt(2)" ::: "memory");
        } else {
          asm volatile("s_waitcnt vmcnt(0)" ::: "memory");
        }
      }
      if (ph == 3 && hasNext) asm volatile("s_waitcnt vmcnt(2)" ::: "memory");
      __builtin_amdgcn_s_barrier();
    }
  }
#undef STAGE_A
#undef STAGE_B

  // ---- epilogue ----
  const long cbase = blockIdx.z * batchC;
  const int crow = blockIdx.y * BM;
  const int ccol = blockIdx.x * 256;
#pragma unroll
  for (int m = 0; m < MF; ++m) {
    const int qm = m / (MF / 2), ml = m % (MF / 2);
    const int r0 = crow + qm * (BM / 2) + wr * (BM / 4) + ml * 16 + hi * 4;
#pragma unroll
    for (int n = 0; n < 4; ++n) {
      const int qn = n >> 1, nl = n & 1;
      const int c = ccol + qn * 128 + wc * 32 + nl * 16 + fr;
      const float bb = bias ? bias[c] : 0.0f;
#pragma unroll
      for (int j = 0; j < 4; ++j) {
        float v = acc[m][n][j] + bb;
        if (relu) v = fmaxf(v, 0.0f);
        const long idx = cbase + (long)(r0 + j) * N + c;
        if (BF16OUT) ((u16*)Cout)[idx] = f2bf(v);
        else         ((float*)Cout)[idx] = v;
      }
    }
  }
}

// ---------------------------------------------------------------------------
extern "C" void kernel_launch(void* const* d_in, const int* in_sizes, int n_in,
                              void* d_out, int out_size, void* d_ws, size_t ws_size,
                              hipStream_t stream) {
  (void)in_sizes; (void)n_in; (void)out_size; (void)ws_size;
  const float* x  = (const float*)d_in[0];
  const float* Wq = (const float*)d_in[1];
  const float* bq = (const float*)d_in[2];
  const float* Wk = (const float*)d_in[3];
  const float* bk = (const float*)d_in[4];
  const float* Wv = (const float*)d_in[5];
  const float* bv = (const float*)d_in[6];
  const float* W1 = (const float*)d_in[7];
  const float* b1 = (const float*)d_in[8];
  const float* W2 = (const float*)d_in[9];
  const float* b2 = (const float*)d_in[10];
  const float* W3 = (const float*)d_in[11];
  const float* b3 = (const float*)d_in[12];

  char* ws = (char*)d_ws;
  const size_t MB = 1u << 20;
  float* Qf   = (float*)(ws + 0);
  float* Kf   = Qf + (size_t)8192 * 1024;
  float* simf = (float*)(ws + 0);
  u16*   h2   = (u16*)(ws + 0);
  u16* xbf = (u16*)(ws + 64 * MB);
  u16* Vbf = xbf + (size_t)8192 * 1024;
  u16* P   = (u16*)(ws + 64 * MB);
  u16* Wq_b = (u16*)(ws + 96 * MB);
  u16* Wk_b = Wq_b + 1048576;
  u16* Wv_b = Wk_b + 1048576;
  u16* W1_b = Wv_b + 1048576;
  u16* W2_b = W1_b + 1048576;
  u16* W3_b = W2_b + 4194304;
  u16* Qn = (u16*)(ws + 120 * MB);
  u16* Kn = Qn + 8388608;
  u16* Vt = Kn + 8388608;
  u16* attnout = Qn;  // Qn dead after sim GEMM
  u16* h1      = Kn;  // Kn dead after sim GEMM

  // 1. casts
  cast_bf16_kernel<<<8192, 256, 0, stream>>>(x,  xbf,  2097152);
  cast_bf16_kernel<<<1024, 256, 0, stream>>>(Wq, Wq_b, 262144);
  cast_bf16_kernel<<<1024, 256, 0, stream>>>(Wk, Wk_b, 262144);
  cast_bf16_kernel<<<1024, 256, 0, stream>>>(Wv, Wv_b, 262144);
  cast_bf16_kernel<<<1024, 256, 0, stream>>>(W1, W1_b, 262144);
  cast_bf16_kernel<<<4096, 256, 0, stream>>>(W2, W2_b, 1048576);
  cast_bf16_kernel<<<4096, 256, 0, stream>>>(W3, W3_b, 1048576);

  dim3 blk(512);
  // 2. QKV projections (M=8192, N=1024, K=1024)
  gemm8p<128, false><<<dim3(4, 64, 1), blk, 0, stream>>>(xbf, Wq_b, bq, Qf, 1024, 1024, 0, 0, 0, 0);
  gemm8p<128, false><<<dim3(4, 64, 1), blk, 0, stream>>>(xbf, Wk_b, bk, Kf, 1024, 1024, 0, 0, 0, 0);
  gemm8p<128, true ><<<dim3(4, 64, 1), blk, 0, stream>>>(xbf, Wv_b, bv, Vbf, 1024, 1024, 0, 0, 0, 0);
  // 3. normalize + transpose
  l2norm_kernel<<<8192, 256, 0, stream>>>(Qf, Qn);
  l2norm_kernel<<<8192, 256, 0, stream>>>(Kf, Kn);
  transpose_kernel<<<dim3(32, 64, 4), dim3(32, 8), 0, stream>>>(Vbf, Vt, 2048, 1024);
  // 4. sim = Qn @ Kn^T per batch (M=N=2048, K=1024)
  gemm8p<256, false><<<dim3(8, 8, 4), blk, 0, stream>>>(Qn, Kn, nullptr, simf,
      2048, 1024, 2097152L, 2097152L, 4194304L, 0);
  // 5. softmax
  softmax_kernel<<<8192, 256, 0, stream>>>(simf, P);
  // 6. attnout = P @ V (M=2048, N=1024, K=2048, per batch)
  gemm8p<128, true><<<dim3(4, 16, 4), blk, 0, stream>>>(P, Vt, nullptr, attnout,
      1024, 2048, 4194304L, 2097152L, 2097152L, 0);
  // 7. MLP
  gemm8p<128, true ><<<dim3(4, 64, 1), blk, 0, stream>>>(attnout, W1_b, b1, h1, 1024, 1024, 0, 0, 0, 1);
  gemm8p<256, true ><<<dim3(16, 32, 1), blk, 0, stream>>>(h1, W2_b, b2, h2, 4096, 1024, 0, 0, 0, 1);
  gemm8p<128, false><<<dim3(4, 64, 1), blk, 0, stream>>>(h2, W3_b, b3, (float*)d_out, 1024, 4096, 0, 0, 0, 0);
}

// Round 3
// 445.941 us; speedup vs baseline: 1.2057x; 1.0868x over previous
//
#include <hip/hip_runtime.h>

// ---------------------------------------------------------------------------
// Cosine-attention transformer block, MI355X gfx950.  Round 3.
//
// GEMM template (T1+T2+T3+T4+T5):
//   BN=256, BK=64, 512 threads = 8 waves (2M x 4N).  BM in {128,256}.
//   DEPTH = LDS pipeline depth: BM=256 -> 2 (128 KB), BM=128 -> 3 (144 KB).
//   Phase (qm,qn): ph0=(0,0) ph1=(1,0) ph2=(0,1) ph3=(1,1); phase reads one
//   A-half x one B-half.  XOR swizzle granule^=row&7 -> conflict-free ds_read.
//   Staged via global_load_lds w=16, pre-swizzled per-lane source (m173).
//
//   DEPTH=2 (BM=256, L=8 loads/thread/tile: A r0..3, B r0..3):
//     iter t stages tile t+1 spread over phases {A01,A23,B01,B23};
//     ph1: vmcnt(4) -> Bh1(t) landed (needed ph2); ph3: vmcnt(2) ->
//     A(t+1),Bh0(t+1) landed; Bh1(t+1) covered by ph1-of-t+1's vmcnt(4).
//   DEPTH=3 (BM=128, L=6: A r0,r1, B r0..3):
//     iter t stages tile t+2 (buffer (t+2)%3 == buffer of t-1, consumed and
//     barrier-separated).  Single wait at ph3: if tile t+2 was staged,
//     vmcnt(6) leaves exactly those 6 in flight -> tile t+1 fully landed.
//     If staging stopped (t+2>=NT), vmcnt(0) drains (tail iterations only;
//     vmcnt(6) would NOT guarantee tile t+1 in that case).
//   Prologue DEPTH=3: stage tiles 0,1; vmcnt(6) -> tile 0 landed.
//
//   Grid is 1-D; kernel decomposes with XCD-bijective swizzle (m204) so each
//   XCD owns a contiguous run of x-major tile ids (A-panel L2 reuse).
// ---------------------------------------------------------------------------

using u16 = unsigned short;
using bf16x8 = __attribute__((ext_vector_type(8))) __bf16;
using f32x4  = __attribute__((ext_vector_type(4))) float;

__device__ __forceinline__ u16 f2bf(float f) {
  unsigned u = __float_as_uint(f);
  unsigned r = (u + 0x7FFFu + ((u >> 16) & 1u)) >> 16;
  return (u16)r;
}

// ---------------- fp32 -> bf16 cast (vectorized x4) ----------------
__global__ __launch_bounds__(256) void cast_bf16_kernel(
    const float* __restrict__ in, u16* __restrict__ out, int n4) {
  int i = blockIdx.x * 256 + threadIdx.x;
  if (i < n4) {
    float4 v = reinterpret_cast<const float4*>(in)[i];
    ushort4 o;
    o.x = f2bf(v.x); o.y = f2bf(v.y); o.z = f2bf(v.z); o.w = f2bf(v.w);
    reinterpret_cast<ushort4*>(out)[i] = o;
  }
}

// ---------------- row L2-normalize: f32 [rows][1024] -> bf16 ----------------
__global__ __launch_bounds__(256) void l2norm_kernel(
    const float* __restrict__ in, u16* __restrict__ out) {
  __shared__ float red[4];
  long row = blockIdx.x;
  const int tid = threadIdx.x, lane = tid & 63, wave = tid >> 6;
  const float* p = in + row * 1024;
  float4 x = *reinterpret_cast<const float4*>(p + tid * 4);
  float ss = x.x * x.x + x.y * x.y + x.z * x.z + x.w * x.w;
#pragma unroll
  for (int o = 32; o; o >>= 1) ss += __shfl_xor(ss, o);
  if (lane == 0) red[wave] = ss;
  __syncthreads();
  ss = red[0] + red[1] + red[2] + red[3];
  float s = 1.0f / fmaxf(sqrtf(ss), 1e-12f);
  ushort4 o;
  o.x = f2bf(x.x * s); o.y = f2bf(x.y * s); o.z = f2bf(x.z * s); o.w = f2bf(x.w * s);
  *reinterpret_cast<ushort4*>(out + row * 1024 + tid * 4) = o;
}

// ---------------- bf16 transpose: in [rows][cols] -> out [cols][rows] -------
__global__ void transpose_kernel(const u16* __restrict__ in, u16* __restrict__ out,
                                 int rows, int cols) {
  __shared__ u16 t[32][33];
  const int c0 = blockIdx.x * 32, r0 = blockIdx.y * 32;
  const long off = (long)blockIdx.z * rows * cols;
  const u16* ib = in + off;
  u16* ob = out + off;
  const int tx = threadIdx.x, ty = threadIdx.y;  // (32, 8)
#pragma unroll
  for (int j = 0; j < 4; ++j)
    t[ty + j * 8][tx] = ib[(long)(r0 + ty + j * 8) * cols + c0 + tx];
  __syncthreads();
#pragma unroll
  for (int j = 0; j < 4; ++j)
    ob[(long)(c0 + ty + j * 8) * rows + r0 + tx] = t[tx][ty + j * 8];
}

// ---------------- row softmax: f32 [rows][2048] -> bf16 ----------------
__global__ __launch_bounds__(256) void softmax_kernel(
    const float* __restrict__ in, u16* __restrict__ out) {
  __shared__ float red[4];
  long row = blockIdx.x;
  const int tid = threadIdx.x, lane = tid & 63, wave = tid >> 6;
  const float* p = in + row * 2048;
  float v[8];
  float4 a = *reinterpret_cast<const float4*>(p + tid * 8);
  float4 b = *reinterpret_cast<const float4*>(p + tid * 8 + 4);
  v[0] = a.x; v[1] = a.y; v[2] = a.z; v[3] = a.w;
  v[4] = b.x; v[5] = b.y; v[6] = b.z; v[7] = b.w;
  float m = v[0];
#pragma unroll
  for (int i = 1; i < 8; ++i) m = fmaxf(m, v[i]);
#pragma unroll
  for (int o = 32; o; o >>= 1) m = fmaxf(m, __shfl_xor(m, o));
  if (lane == 0) red[wave] = m;
  __syncthreads();
  m = fmaxf(fmaxf(red[0], red[1]), fmaxf(red[2], red[3]));
  float s = 0.0f;
#pragma unroll
  for (int i = 0; i < 8; ++i) { v[i] = __expf(v[i] - m); s += v[i]; }
#pragma unroll
  for (int o = 32; o; o >>= 1) s += __shfl_xor(s, o);
  __syncthreads();
  if (lane == 0) red[wave] = s;
  __syncthreads();
  s = red[0] + red[1] + red[2] + red[3];
  float inv = 1.0f / s;
  ushort4 o0, o1;
  o0.x = f2bf(v[0] * inv); o0.y = f2bf(v[1] * inv);
  o0.z = f2bf(v[2] * inv); o0.w = f2bf(v[3] * inv);
  o1.x = f2bf(v[4] * inv); o1.y = f2bf(v[5] * inv);
  o1.z = f2bf(v[6] * inv); o1.w = f2bf(v[7] * inv);
  *reinterpret_cast<ushort4*>(out + row * 2048 + tid * 8) = o0;
  *reinterpret_cast<ushort4*>(out + row * 2048 + tid * 8 + 4) = o1;
}

// ---------------- 8-phase bf16 NT GEMM ----------------
// C[m,n] = sum_k A[m,k]*B[n,k] (+bias[n]) (+relu).
// MODE: 0 = f32 out, 1 = bf16 out, 2 = QKV column-route (BM=256 only):
//   cols [0,1024)->Cout f32/bias, [1024,2048)->Cout2 f32/bias2,
//   [2048,3072)->Cout3 bf16/bias3.
// Launched as 1-D grid of gx*gy*gz blocks, x-major.
template <int BM, int DEPTH, int MODE>
__global__ __launch_bounds__(512, 2) void gemm8p(
    const u16* __restrict__ A, const u16* __restrict__ Bw,
    const float* __restrict__ bias, void* __restrict__ Cout,
    const float* __restrict__ bias2, void* __restrict__ Cout2,
    const float* __restrict__ bias3, void* __restrict__ Cout3,
    int N, int K, long batchA, long batchB, long batchC, int relu,
    int gx, int gy) {
  static_assert(MODE != 2 || BM == 256, "QKV route assumes BM=256");
  constexpr int MF  = BM / 32;        // m-frags per wave (8 or 4)
  constexpr int ASZ = BM * 64;        // u16 per A buffer
  constexpr int BSZ = 256 * 64;
  constexpr int AR  = BM / 64;        // A stage rounds per K-tile (4 or 2)
  __shared__ u16 lds[DEPTH * (ASZ + BSZ)];
  u16* const ldsA = lds;
  u16* const ldsB = lds + DEPTH * ASZ;

  // ---- XCD-bijective block swizzle (m204) ----
  const int nwg = gridDim.x;
  {
  }
  const int lid = blockIdx.x;
  const int q = nwg >> 3, r = nwg & 7;
  const int xcd = lid & 7, jj = lid >> 3;
  const int wg = (xcd < r ? xcd * (q + 1) : r * (q + 1) + (xcd - r) * q) + jj;
  const int bx = wg % gx;
  const int rest = wg / gx;
  const int by = rest % gy;
  const int bz = rest / gy;

  const int tid = threadIdx.x, wave = tid >> 6, lane = tid & 63;
  const int wr = wave >> 2, wc = wave & 3;
  const int fr = lane & 15, hi = lane >> 4;

  const long Abase = bz * batchA + (long)by * BM * K;
  const long Bbase = bz * batchB + (long)bx * 256 * K;

  // ---- precomputed swizzled ds_read offsets (u16 units) ----
  int aoff[MF][2], boff[4][2];
#pragma unroll
  for (int m = 0; m < MF; ++m) {
    const int qm = m / (MF / 2), ml = m % (MF / 2);
    const int row = qm * (BM / 2) + wr * (BM / 4) + ml * 16 + fr;
#pragma unroll
    for (int ks = 0; ks < 2; ++ks) {
      const int gg = ks * 4 + hi;
      aoff[m][ks] = row * 64 + ((gg ^ (row & 7)) * 8);
    }
  }
#pragma unroll
  for (int n = 0; n < 4; ++n) {
    const int qn = n >> 1, nl = n & 1;
    const int row = qn * 128 + wc * 32 + nl * 16 + fr;
#pragma unroll
    for (int ks = 0; ks < 2; ++ks) {
      const int gg = ks * 4 + hi;
      boff[n][ks] = row * 64 + ((gg ^ (row & 7)) * 8);
    }
  }

  // ---- stage source offsets (pre-swizzled global, m173) ----
  const int rA = wave * 8 + (lane >> 3);
  const int g8 = (((lane & 7) ^ (lane >> 3)) * 8);
  long asrc[AR], bsrc[4];
#pragma unroll
  for (int rr = 0; rr < AR; ++rr) asrc[rr] = Abase + (long)(rr * 64 + rA) * K + g8;
#pragma unroll
  for (int rr = 0; rr < 4; ++rr) bsrc[rr] = Bbase + (long)(rr * 64 + rA) * K + g8;

#define STAGE_A(bufp, rr, k0)                                                  \
  __builtin_amdgcn_global_load_lds(                                            \
      (const __attribute__((address_space(1))) void*)(A + asrc[rr] + (k0)),    \
      (__attribute__((address_space(3))) void*)((bufp) + (rr) * 4096 + wave * 512), \
      16, 0, 0)
#define STAGE_B(bufp, rr, k0)                                                  \
  __builtin_amdgcn_global_load_lds(                                            \
      (const __attribute__((address_space(1))) void*)(Bw + bsrc[rr] + (k0)),   \
      (__attribute__((address_space(3))) void*)((bufp) + (rr) * 4096 + wave * 512), \
      16, 0, 0)

  const int NT = K >> 6;

  // ---- prologue ----
  if constexpr (DEPTH == 2) {
#pragma unroll
    for (int rr = 0; rr < AR; ++rr) STAGE_A(ldsA, rr, 0);
#pragma unroll
    for (int rr = 0; rr < 4; ++rr) STAGE_B(ldsB, rr, 0);
    asm volatile("s_waitcnt vmcnt(0)" ::: "memory");
  } else {
#pragma unroll
    for (int rr = 0; rr < AR; ++rr) STAGE_A(ldsA, rr, 0);
#pragma unroll
    for (int rr = 0; rr < 4; ++rr) STAGE_B(ldsB, rr, 0);
    if (NT > 1) {
#pragma unroll
      for (int rr = 0; rr < AR; ++rr) STAGE_A(ldsA + ASZ, rr, 64);
#pragma unroll
      for (int rr = 0; rr < 4; ++rr) STAGE_B(ldsB + BSZ, rr, 64);
      asm volatile("s_waitcnt vmcnt(6)" ::: "memory");  // L=6: tile 0 landed
    } else {
      asm volatile("s_waitcnt vmcnt(0)" ::: "memory");
    }
  }
  __builtin_amdgcn_s_barrier();

  f32x4 acc[MF][4] = {};

  for (int t = 0; t < NT; ++t) {
    u16* curA = ldsA + (t % DEPTH) * ASZ;
    u16* curB = ldsB + (t % DEPTH) * BSZ;
    const int ts = t + DEPTH - 1;      // tile to stage this iteration
    const bool st = ts < NT;
    u16* nxtA = ldsA + (ts % DEPTH) * ASZ;
    u16* nxtB = ldsB + (ts % DEPTH) * BSZ;
    const int k0n = ts << 6;

#pragma unroll
    for (int ph = 0; ph < 4; ++ph) {
      const int qm = ph & 1, qn = ph >> 1;
      bf16x8 af[MF / 2][2], bf[2][2];
#pragma unroll
      for (int mm = 0; mm < MF / 2; ++mm)
#pragma unroll
        for (int ks = 0; ks < 2; ++ks)
          af[mm][ks] = *reinterpret_cast<const bf16x8*>(
              &curA[aoff[qm * (MF / 2) + mm][ks]]);
#pragma unroll
      for (int nn = 0; nn < 2; ++nn)
#pragma unroll
        for (int ks = 0; ks < 2; ++ks)
          bf[nn][ks] = *reinterpret_cast<const bf16x8*>(
              &curB[boff[qn * 2 + nn][ks]]);
      if (st) {
        if (ph == 0) {
#pragma unroll
          for (int rr = 0; rr < AR / 2; ++rr) STAGE_A(nxtA, rr, k0n);
        } else if (ph == 1) {
#pragma unroll
          for (int rr = AR / 2; rr < AR; ++rr) STAGE_A(nxtA, rr, k0n);
        } else if (ph == 2) {
          STAGE_B(nxtB, 0, k0n); STAGE_B(nxtB, 1, k0n);
        } else {
          STAGE_B(nxtB, 2, k0n); STAGE_B(nxtB, 3, k0n);
        }
      }
      __builtin_amdgcn_s_barrier();
      __builtin_amdgcn_s_setprio(1);
#pragma unroll
      for (int ks = 0; ks < 2; ++ks)
#pragma unroll
        for (int mm = 0; mm < MF / 2; ++mm)
#pragma unroll
          for (int nn = 0; nn < 2; ++nn)
            acc[qm * (MF / 2) + mm][qn * 2 + nn] =
                __builtin_amdgcn_mfma_f32_16x16x32_bf16(
                    af[mm][ks], bf[nn][ks],
                    acc[qm * (MF / 2) + mm][qn * 2 + nn], 0, 0, 0);
      __builtin_amdgcn_s_setprio(0);
      if constexpr (DEPTH == 2) {
        if (ph == 1) {
          if (st) asm volatile("s_waitcnt vmcnt(4)" ::: "memory");
          else    asm volatile("s_waitcnt vmcnt(0)" ::: "memory");
        }
        if (ph == 3 && st) asm volatile("s_waitcnt vmcnt(2)" ::: "memory");
      } else {
        if (ph == 3) {
          if (st) asm volatile("s_waitcnt vmcnt(6)" ::: "memory");
          else    asm volatile("s_waitcnt vmcnt(0)" ::: "memory");
        }
      }
      __builtin_amdgcn_s_barrier();
    }
  }
#undef STAGE_A
#undef STAGE_B

  // ---- epilogue ----
  const long cbase = bz * batchC;
  const int crow = by * BM;
  int ccol = bx * 256;
  const float* bp = bias;
  void* cp = Cout;
  bool obf = (MODE == 1);
  int Nst = N;
  if constexpr (MODE == 2) {
    const int sel = ccol >> 10;  // block-uniform: 256 | 1024
    if (sel == 1) { bp = bias2; cp = Cout2; }
    else if (sel == 2) { bp = bias3; cp = Cout3; obf = true; }
    ccol &= 1023;
    Nst = 1024;
  }
#pragma unroll
  for (int m = 0; m < MF; ++m) {
    const int qm = m / (MF / 2), ml = m % (MF / 2);
    const int r0 = crow + qm * (BM / 2) + wr * (BM / 4) + ml * 16 + hi * 4;
#pragma unroll
    for (int n = 0; n < 4; ++n) {
      const int qn = n >> 1, nl = n & 1;
      const int c = ccol + qn * 128 + wc * 32 + nl * 16 + fr;
      const float bb = bp ? bp[c] : 0.0f;
#pragma unroll
      for (int j = 0; j < 4; ++j) {
        float v = acc[m][n][j] + bb;
        if (relu) v = fmaxf(v, 0.0f);
        const long idx = cbase + (long)(r0 + j) * Nst + c;
        if (obf) ((u16*)cp)[idx] = f2bf(v);
        else     ((float*)cp)[idx] = v;
      }
    }
  }
}

// ---------------------------------------------------------------------------
extern "C" void kernel_launch(void* const* d_in, const int* in_sizes, int n_in,
                              void* d_out, int out_size, void* d_ws, size_t ws_size,
                              hipStream_t stream) {
  (void)in_sizes; (void)n_in; (void)out_size; (void)ws_size;
  const float* x  = (const float*)d_in[0];
  const float* Wq = (const float*)d_in[1];
  const float* bq = (const float*)d_in[2];
  const float* Wk = (const float*)d_in[3];
  const float* bk = (const float*)d_in[4];
  const float* Wv = (const float*)d_in[5];
  const float* bv = (const float*)d_in[6];
  const float* W1 = (const float*)d_in[7];
  const float* b1 = (const float*)d_in[8];
  const float* W2 = (const float*)d_in[9];
  const float* b2 = (const float*)d_in[10];
  const float* W3 = (const float*)d_in[11];
  const float* b3 = (const float*)d_in[12];

  char* ws = (char*)d_ws;
  const size_t MB = 1u << 20;
  float* Qf   = (float*)(ws + 0);
  float* Kf   = Qf + (size_t)8192 * 1024;
  float* simf = (float*)(ws + 0);
  u16*   h2   = (u16*)(ws + 0);
  u16* xbf = (u16*)(ws + 64 * MB);
  u16* Vbf = xbf + (size_t)8192 * 1024;
  u16* P   = (u16*)(ws + 64 * MB);
  u16* Wq_b = (u16*)(ws + 96 * MB);   // Wq,Wk,Wv contiguous -> [3072][1024]
  u16* Wk_b = Wq_b + 1048576;
  u16* Wv_b = Wk_b + 1048576;
  u16* W1_b = Wv_b + 1048576;
  u16* W2_b = W1_b + 1048576;
  u16* W3_b = W2_b + 4194304;
  u16* Qn = (u16*)(ws + 120 * MB);
  u16* Kn = Qn + 8388608;
  u16* Vt = Kn + 8388608;
  u16* attnout = Qn;  // Qn dead after sim GEMM
  u16* h1      = Kn;  // Kn dead after sim GEMM

  // 1. casts
  cast_bf16_kernel<<<8192, 256, 0, stream>>>(x,  xbf,  2097152);
  cast_bf16_kernel<<<1024, 256, 0, stream>>>(Wq, Wq_b, 262144);
  cast_bf16_kernel<<<1024, 256, 0, stream>>>(Wk, Wk_b, 262144);
  cast_bf16_kernel<<<1024, 256, 0, stream>>>(Wv, Wv_b, 262144);
  cast_bf16_kernel<<<1024, 256, 0, stream>>>(W1, W1_b, 262144);
  cast_bf16_kernel<<<4096, 256, 0, stream>>>(W2, W2_b, 1048576);
  cast_bf16_kernel<<<4096, 256, 0, stream>>>(W3, W3_b, 1048576);

  // 2. fused QKV: M=8192, N=3072, K=1024  (BM=256, grid 12x32=384)
  gemm8p<256, 2, 2><<<dim3(12 * 32), 512, 0, stream>>>(
      xbf, Wq_b, bq, Qf, bk, Kf, bv, Vbf, 3072, 1024, 0, 0, 0, 0, 12, 32);
  // 3. normalize + transpose
  l2norm_kernel<<<8192, 256, 0, stream>>>(Qf, Qn);
  l2norm_kernel<<<8192, 256, 0, stream>>>(Kf, Kn);
  transpose_kernel<<<dim3(32, 64, 4), dim3(32, 8), 0, stream>>>(Vbf, Vt, 2048, 1024);
  // 4. sim = Qn @ Kn^T per batch (M=N=2048, K=1024; grid 8x8x4=256)
  gemm8p<256, 2, 0><<<dim3(8 * 8 * 4), 512, 0, stream>>>(
      Qn, Kn, nullptr, simf, nullptr, nullptr, nullptr, nullptr,
      2048, 1024, 2097152L, 2097152L, 4194304L, 0, 8, 8);
  // 5. softmax
  softmax_kernel<<<8192, 256, 0, stream>>>(simf, P);
  // 6. attnout = P @ V (M=2048, N=1024, K=2048, per batch; grid 4x16x4=256)
  gemm8p<128, 3, 1><<<dim3(4 * 16 * 4), 512, 0, stream>>>(
      P, Vt, nullptr, attnout, nullptr, nullptr, nullptr, nullptr,
      1024, 2048, 4194304L, 2097152L, 2097152L, 0, 4, 16);
  // 7. MLP
  gemm8p<128, 3, 1><<<dim3(4 * 64), 512, 0, stream>>>(
      attnout, W1_b, b1, h1, nullptr, nullptr, nullptr, nullptr,
      1024, 1024, 0, 0, 0, 1, 4, 64);
  gemm8p<256, 2, 1><<<dim3(16 * 32), 512, 0, stream>>>(
      h1, W2_b, b2, h2, nullptr, nullptr, nullptr, nullptr,
      4096, 1024, 0, 0, 0, 1, 16, 32);
  gemm8p<128, 3, 0><<<dim3(4 * 64), 512, 0, stream>>>(
      h2, W3_b, b3, (float*)d_out, nullptr, nullptr, nullptr, nullptr,
      1024, 4096, 0, 0, 0, 0, 4, 64);
}

// Round 4
// 403.670 us; speedup vs baseline: 1.3319x; 1.1047x over previous
//
#include <hip/hip_runtime.h>

// ---------------------------------------------------------------------------
// Cosine-attention transformer block, MI355X gfx950.  Round 4: frag-once LDS.
//
// GEMM (T1+T2+T3+T4+T5): BN=256, BK=64, 512 thr = 8 waves (2M x 4N).
// BM in {128,256}; DEPTH: BM=256 -> 2 (128 KB LDS), BM=128 -> 3 (144 KB).
// XOR swizzle granule^=row&7; staged via global_load_lds w=16 with
// pre-swizzled per-lane source (m173).
//
// Frag-once phase order (each A/B half ds_read ONCE per K-tile; halves kept
// live in regs; halves: Ah0/Ah1 = row halves of A-tile, Bh0/Bh1 of B-tile):
//   ph0: read Ah0,Bh0; stage; bar; MFMA q(0,0); [D2 wait]; bar
//   ph1: read Bh1;     stage; bar; MFMA q(0,1);            bar
//   ph2: read Ah1;     stage; bar; MFMA q(1,0);            bar   (Bh0 live)
//   ph3:               stage; bar; MFMA q(1,1); [wait];    bar
// Staging per phase: ph0 A-rows first half, ph1 A second, ph2 B01, ph3 B23.
//
// vmcnt derivation, DEPTH=2 (L=8/thread/tile; iter t stages tile t+1):
//   ph0-end: outstanding = B23(t)[2, issued iter t-1 ph3] + A01(t+1)[2] = 4;
//     vmcnt(2) -> B23(t) landed; barrier -> ph1 may read Bh1(t).   [st]
//     (!st: vmcnt(0).)
//   ph2 reads Ah1(t) = A23(t), issued iter t-1 ph1: landed by ph0's vmcnt(2)
//     (only A01(t+1) newer).  ph3-end: outstanding = 8; vmcnt(2) -> A(t+1),
//     B01(t+1) landed; B23(t+1) covered by next ph0's vmcnt(2).
// DEPTH=3 (L=6; iter t stages tile t+2 into buffer of t-1, consumed &
//   barrier-separated): single ph3-end wait: st ? vmcnt(6) [-> tile t+1
//   fully landed] : vmcnt(0).  All reads of tile t were guaranteed at iter
//   t-1's ph3 wait.
// ---------------------------------------------------------------------------

using u16 = unsigned short;
using bf16x8 = __attribute__((ext_vector_type(8))) __bf16;
using f32x4  = __attribute__((ext_vector_type(4))) float;

__device__ __forceinline__ u16 f2bf(float f) {
  unsigned u = __float_as_uint(f);
  unsigned r = (u + 0x7FFFu + ((u >> 16) & 1u)) >> 16;
  return (u16)r;
}

// ---------------- fp32 -> bf16 cast (vectorized x4) ----------------
__global__ __launch_bounds__(256) void cast_bf16_kernel(
    const float* __restrict__ in, u16* __restrict__ out, int n4) {
  int i = blockIdx.x * 256 + threadIdx.x;
  if (i < n4) {
    float4 v = reinterpret_cast<const float4*>(in)[i];
    ushort4 o;
    o.x = f2bf(v.x); o.y = f2bf(v.y); o.z = f2bf(v.z); o.w = f2bf(v.w);
    reinterpret_cast<ushort4*>(out)[i] = o;
  }
}

// ---------------- row L2-normalize: f32 [rows][1024] -> bf16 ----------------
__global__ __launch_bounds__(256) void l2norm_kernel(
    const float* __restrict__ in, u16* __restrict__ out) {
  __shared__ float red[4];
  long row = blockIdx.x;
  const int tid = threadIdx.x, lane = tid & 63, wave = tid >> 6;
  const float* p = in + row * 1024;
  float4 x = *reinterpret_cast<const float4*>(p + tid * 4);
  float ss = x.x * x.x + x.y * x.y + x.z * x.z + x.w * x.w;
#pragma unroll
  for (int o = 32; o; o >>= 1) ss += __shfl_xor(ss, o);
  if (lane == 0) red[wave] = ss;
  __syncthreads();
  ss = red[0] + red[1] + red[2] + red[3];
  float s = 1.0f / fmaxf(sqrtf(ss), 1e-12f);
  ushort4 o;
  o.x = f2bf(x.x * s); o.y = f2bf(x.y * s); o.z = f2bf(x.z * s); o.w = f2bf(x.w * s);
  *reinterpret_cast<ushort4*>(out + row * 1024 + tid * 4) = o;
}

// ---------------- bf16 transpose: in [rows][cols] -> out [cols][rows] -------
__global__ void transpose_kernel(const u16* __restrict__ in, u16* __restrict__ out,
                                 int rows, int cols) {
  __shared__ u16 t[32][33];
  const int c0 = blockIdx.x * 32, r0 = blockIdx.y * 32;
  const long off = (long)blockIdx.z * rows * cols;
  const u16* ib = in + off;
  u16* ob = out + off;
  const int tx = threadIdx.x, ty = threadIdx.y;  // (32, 8)
#pragma unroll
  for (int j = 0; j < 4; ++j)
    t[ty + j * 8][tx] = ib[(long)(r0 + ty + j * 8) * cols + c0 + tx];
  __syncthreads();
#pragma unroll
  for (int j = 0; j < 4; ++j)
    ob[(long)(c0 + ty + j * 8) * rows + r0 + tx] = t[tx][ty + j * 8];
}

// ---------------- row softmax: f32 [rows][2048] -> bf16 ----------------
__global__ __launch_bounds__(256) void softmax_kernel(
    const float* __restrict__ in, u16* __restrict__ out) {
  __shared__ float red[4];
  long row = blockIdx.x;
  const int tid = threadIdx.x, lane = tid & 63, wave = tid >> 6;
  const float* p = in + row * 2048;
  float v[8];
  float4 a = *reinterpret_cast<const float4*>(p + tid * 8);
  float4 b = *reinterpret_cast<const float4*>(p + tid * 8 + 4);
  v[0] = a.x; v[1] = a.y; v[2] = a.z; v[3] = a.w;
  v[4] = b.x; v[5] = b.y; v[6] = b.z; v[7] = b.w;
  float m = v[0];
#pragma unroll
  for (int i = 1; i < 8; ++i) m = fmaxf(m, v[i]);
#pragma unroll
  for (int o = 32; o; o >>= 1) m = fmaxf(m, __shfl_xor(m, o));
  if (lane == 0) red[wave] = m;
  __syncthreads();
  m = fmaxf(fmaxf(red[0], red[1]), fmaxf(red[2], red[3]));
  float s = 0.0f;
#pragma unroll
  for (int i = 0; i < 8; ++i) { v[i] = __expf(v[i] - m); s += v[i]; }
#pragma unroll
  for (int o = 32; o; o >>= 1) s += __shfl_xor(s, o);
  __syncthreads();
  if (lane == 0) red[wave] = s;
  __syncthreads();
  s = red[0] + red[1] + red[2] + red[3];
  float inv = 1.0f / s;
  ushort4 o0, o1;
  o0.x = f2bf(v[0] * inv); o0.y = f2bf(v[1] * inv);
  o0.z = f2bf(v[2] * inv); o0.w = f2bf(v[3] * inv);
  o1.x = f2bf(v[4] * inv); o1.y = f2bf(v[5] * inv);
  o1.z = f2bf(v[6] * inv); o1.w = f2bf(v[7] * inv);
  *reinterpret_cast<ushort4*>(out + row * 2048 + tid * 8) = o0;
  *reinterpret_cast<ushort4*>(out + row * 2048 + tid * 8 + 4) = o1;
}

// ---------------- 8-phase bf16 NT GEMM (frag-once reads) ----------------
// C[m,n] = sum_k A[m,k]*B[n,k] (+bias[n]) (+relu).
// MODE: 0 = f32 out, 1 = bf16 out, 2 = QKV column-route (BM=256 only).
// Launched as 1-D grid of gx*gy*gz blocks, x-major.
template <int BM, int DEPTH, int MODE>
__global__ __launch_bounds__(512, 2) void gemm8p(
    const u16* __restrict__ A, const u16* __restrict__ Bw,
    const float* __restrict__ bias, void* __restrict__ Cout,
    const float* __restrict__ bias2, void* __restrict__ Cout2,
    const float* __restrict__ bias3, void* __restrict__ Cout3,
    int N, int K, long batchA, long batchB, long batchC, int relu,
    int gx, int gy) {
  static_assert(MODE != 2 || BM == 256, "QKV route assumes BM=256");
  constexpr int MF  = BM / 32;        // m-frags per wave (8 or 4)
  constexpr int MH  = MF / 2;         // m-frags per half
  constexpr int ASZ = BM * 64;        // u16 per A buffer
  constexpr int BSZ = 256 * 64;
  constexpr int AR  = BM / 64;        // A stage rounds per K-tile (4 or 2)
  __shared__ u16 lds[DEPTH * (ASZ + BSZ)];
  u16* const ldsA = lds;
  u16* const ldsB = lds + DEPTH * ASZ;

  // ---- XCD-bijective block swizzle (m204) ----
  const int nwg = gridDim.x;
  const int lid = blockIdx.x;
  const int q = nwg >> 3, r = nwg & 7;
  const int xcd = lid & 7, jj = lid >> 3;
  const int wg = (xcd < r ? xcd * (q + 1) : r * (q + 1) + (xcd - r) * q) + jj;
  const int bx = wg % gx;
  const int rest = wg / gx;
  const int by = rest % gy;
  const int bz = rest / gy;

  const int tid = threadIdx.x, wave = tid >> 6, lane = tid & 63;
  const int wr = wave >> 2, wc = wave & 3;
  const int fr = lane & 15, hi = lane >> 4;

  const long Abase = bz * batchA + (long)by * BM * K;
  const long Bbase = bz * batchB + (long)bx * 256 * K;

  // ---- precomputed swizzled ds_read offsets (u16 units) ----
  int aoff[MF][2], boff[4][2];
#pragma unroll
  for (int m = 0; m < MF; ++m) {
    const int qm = m / MH, ml = m % MH;
    const int row = qm * (BM / 2) + wr * (BM / 4) + ml * 16 + fr;
#pragma unroll
    for (int ks = 0; ks < 2; ++ks) {
      const int gg = ks * 4 + hi;
      aoff[m][ks] = row * 64 + ((gg ^ (row & 7)) * 8);
    }
  }
#pragma unroll
  for (int n = 0; n < 4; ++n) {
    const int qn = n >> 1, nl = n & 1;
    const int row = qn * 128 + wc * 32 + nl * 16 + fr;
#pragma unroll
    for (int ks = 0; ks < 2; ++ks) {
      const int gg = ks * 4 + hi;
      boff[n][ks] = row * 64 + ((gg ^ (row & 7)) * 8);
    }
  }

  // ---- stage source offsets (pre-swizzled global, m173) ----
  const int rA = wave * 8 + (lane >> 3);
  const int g8 = (((lane & 7) ^ (lane >> 3)) * 8);
  long asrc[AR], bsrc[4];
#pragma unroll
  for (int rr = 0; rr < AR; ++rr) asrc[rr] = Abase + (long)(rr * 64 + rA) * K + g8;
#pragma unroll
  for (int rr = 0; rr < 4; ++rr) bsrc[rr] = Bbase + (long)(rr * 64 + rA) * K + g8;

#define STAGE_A(bufp, rr, k0)                                                  \
  __builtin_amdgcn_global_load_lds(                                            \
      (const __attribute__((address_space(1))) void*)(A + asrc[rr] + (k0)),    \
      (__attribute__((address_space(3))) void*)((bufp) + (rr) * 4096 + wave * 512), \
      16, 0, 0)
#define STAGE_B(bufp, rr, k0)                                                  \
  __builtin_amdgcn_global_load_lds(                                            \
      (const __attribute__((address_space(1))) void*)(Bw + bsrc[rr] + (k0)),   \
      (__attribute__((address_space(3))) void*)((bufp) + (rr) * 4096 + wave * 512), \
      16, 0, 0)

  const int NT = K >> 6;

  // ---- prologue ----
  if constexpr (DEPTH == 2) {
#pragma unroll
    for (int rr = 0; rr < AR; ++rr) STAGE_A(ldsA, rr, 0);
#pragma unroll
    for (int rr = 0; rr < 4; ++rr) STAGE_B(ldsB, rr, 0);
    asm volatile("s_waitcnt vmcnt(0)" ::: "memory");
  } else {
#pragma unroll
    for (int rr = 0; rr < AR; ++rr) STAGE_A(ldsA, rr, 0);
#pragma unroll
    for (int rr = 0; rr < 4; ++rr) STAGE_B(ldsB, rr, 0);
    if (NT > 1) {
#pragma unroll
      for (int rr = 0; rr < AR; ++rr) STAGE_A(ldsA + ASZ, rr, 64);
#pragma unroll
      for (int rr = 0; rr < 4; ++rr) STAGE_B(ldsB + BSZ, rr, 64);
      asm volatile("s_waitcnt vmcnt(6)" ::: "memory");  // L=6: tile 0 landed
    } else {
      asm volatile("s_waitcnt vmcnt(0)" ::: "memory");
    }
  }
  __builtin_amdgcn_s_barrier();

  f32x4 acc[MF][4] = {};

#define READ_AHALF(dst, h)                                                     \
  _Pragma("unroll") for (int mm = 0; mm < MH; ++mm)                            \
  _Pragma("unroll") for (int ks = 0; ks < 2; ++ks)                             \
    dst[mm][ks] = *reinterpret_cast<const bf16x8*>(&curA[aoff[(h) * MH + mm][ks]]);
#define READ_BHALF(dst, h)                                                     \
  _Pragma("unroll") for (int nn = 0; nn < 2; ++nn)                             \
  _Pragma("unroll") for (int ks = 0; ks < 2; ++ks)                             \
    dst[nn][ks] = *reinterpret_cast<const bf16x8*>(&curB[boff[(h) * 2 + nn][ks]]);
#define MFMA_Q(ah, bh, qm, qn)                                                 \
  __builtin_amdgcn_s_setprio(1);                                               \
  _Pragma("unroll") for (int ks = 0; ks < 2; ++ks)                             \
  _Pragma("unroll") for (int mm = 0; mm < MH; ++mm)                            \
  _Pragma("unroll") for (int nn = 0; nn < 2; ++nn)                             \
    acc[(qm) * MH + mm][(qn) * 2 + nn] =                                       \
        __builtin_amdgcn_mfma_f32_16x16x32_bf16(                               \
            ah[mm][ks], bh[nn][ks], acc[(qm) * MH + mm][(qn) * 2 + nn], 0, 0, 0); \
  __builtin_amdgcn_s_setprio(0);

  for (int t = 0; t < NT; ++t) {
    u16* curA = ldsA + (t % DEPTH) * ASZ;
    u16* curB = ldsB + (t % DEPTH) * BSZ;
    const int ts = t + DEPTH - 1;      // tile staged this iteration
    const bool st = ts < NT;
    u16* nxtA = ldsA + (ts % DEPTH) * ASZ;
    u16* nxtB = ldsB + (ts % DEPTH) * BSZ;
    const int k0n = ts << 6;

    bf16x8 a0[MH][2], a1[MH][2], b0[2][2], b1[2][2];

    // ---- ph0: read Ah0,Bh0 ; MFMA q(0,0) ----
    READ_AHALF(a0, 0)
    READ_BHALF(b0, 0)
    if (st) {
#pragma unroll
      for (int rr = 0; rr < AR / 2; ++rr) STAGE_A(nxtA, rr, k0n);
    }
    __builtin_amdgcn_s_barrier();
    MFMA_Q(a0, b0, 0, 0)
    if constexpr (DEPTH == 2) {
      if (st) asm volatile("s_waitcnt vmcnt(2)" ::: "memory");
      else    asm volatile("s_waitcnt vmcnt(0)" ::: "memory");
    }
    __builtin_amdgcn_s_barrier();

    // ---- ph1: read Bh1 ; MFMA q(0,1) ----
    READ_BHALF(b1, 1)
    if (st) {
#pragma unroll
      for (int rr = AR / 2; rr < AR; ++rr) STAGE_A(nxtA, rr, k0n);
    }
    __builtin_amdgcn_s_barrier();
    MFMA_Q(a0, b1, 0, 1)
    __builtin_amdgcn_s_barrier();

    // ---- ph2: read Ah1 ; MFMA q(1,0) ----
    READ_AHALF(a1, 1)
    if (st) { STAGE_B(nxtB, 0, k0n); STAGE_B(nxtB, 1, k0n); }
    __builtin_amdgcn_s_barrier();
    MFMA_Q(a1, b0, 1, 0)
    __builtin_amdgcn_s_barrier();

    // ---- ph3: MFMA q(1,1) ----
    if (st) { STAGE_B(nxtB, 2, k0n); STAGE_B(nxtB, 3, k0n); }
    __builtin_amdgcn_s_barrier();
    MFMA_Q(a1, b1, 1, 1)
    if constexpr (DEPTH == 2) {
      if (st) asm volatile("s_waitcnt vmcnt(2)" ::: "memory");
    } else {
      if (st) asm volatile("s_waitcnt vmcnt(6)" ::: "memory");
      else    asm volatile("s_waitcnt vmcnt(0)" ::: "memory");
    }
    __builtin_amdgcn_s_barrier();
  }
#undef STAGE_A
#undef STAGE_B
#undef READ_AHALF
#undef READ_BHALF
#undef MFMA_Q

  // ---- epilogue ----
  const long cbase = bz * batchC;
  const int crow = by * BM;
  int ccol = bx * 256;
  const float* bp = bias;
  void* cp = Cout;
  bool obf = (MODE == 1);
  int Nst = N;
  if constexpr (MODE == 2) {
    const int sel = ccol >> 10;  // block-uniform
    if (sel == 1) { bp = bias2; cp = Cout2; }
    else if (sel == 2) { bp = bias3; cp = Cout3; obf = true; }
    ccol &= 1023;
    Nst = 1024;
  }
#pragma unroll
  for (int m = 0; m < MF; ++m) {
    const int qm = m / MH, ml = m % MH;
    const int r0 = crow + qm * (BM / 2) + wr * (BM / 4) + ml * 16 + hi * 4;
#pragma unroll
    for (int n = 0; n < 4; ++n) {
      const int qn = n >> 1, nl = n & 1;
      const int c = ccol + qn * 128 + wc * 32 + nl * 16 + fr;
      const float bb = bp ? bp[c] : 0.0f;
#pragma unroll
      for (int j = 0; j < 4; ++j) {
        float v = acc[m][n][j] + bb;
        if (relu) v = fmaxf(v, 0.0f);
        const long idx = cbase + (long)(r0 + j) * Nst + c;
        if (obf) ((u16*)cp)[idx] = f2bf(v);
        else     ((float*)cp)[idx] = v;
      }
    }
  }
}

// ---------------------------------------------------------------------------
extern "C" void kernel_launch(void* const* d_in, const int* in_sizes, int n_in,
                              void* d_out, int out_size, void* d_ws, size_t ws_size,
                              hipStream_t stream) {
  (void)in_sizes; (void)n_in; (void)out_size; (void)ws_size;
  const float* x  = (const float*)d_in[0];
  const float* Wq = (const float*)d_in[1];
  const float* bq = (const float*)d_in[2];
  const float* Wk = (const float*)d_in[3];
  const float* bk = (const float*)d_in[4];
  const float* Wv = (const float*)d_in[5];
  const float* bv = (const float*)d_in[6];
  const float* W1 = (const float*)d_in[7];
  const float* b1 = (const float*)d_in[8];
  const float* W2 = (const float*)d_in[9];
  const float* b2 = (const float*)d_in[10];
  const float* W3 = (const float*)d_in[11];
  const float* b3 = (const float*)d_in[12];

  char* ws = (char*)d_ws;
  const size_t MB = 1u << 20;
  float* Qf   = (float*)(ws + 0);
  float* Kf   = Qf + (size_t)8192 * 1024;
  float* simf = (float*)(ws + 0);
  u16*   h2   = (u16*)(ws + 0);
  u16* xbf = (u16*)(ws + 64 * MB);
  u16* Vbf = xbf + (size_t)8192 * 1024;
  u16* P   = (u16*)(ws + 64 * MB);
  u16* Wq_b = (u16*)(ws + 96 * MB);   // Wq,Wk,Wv contiguous -> [3072][1024]
  u16* Wk_b = Wq_b + 1048576;
  u16* Wv_b = Wk_b + 1048576;
  u16* W1_b = Wv_b + 1048576;
  u16* W2_b = W1_b + 1048576;
  u16* W3_b = W2_b + 4194304;
  u16* Qn = (u16*)(ws + 120 * MB);
  u16* Kn = Qn + 8388608;
  u16* Vt = Kn + 8388608;
  u16* attnout = Qn;  // Qn dead after sim GEMM
  u16* h1      = Kn;  // Kn dead after sim GEMM

  // 1. casts
  cast_bf16_kernel<<<8192, 256, 0, stream>>>(x,  xbf,  2097152);
  cast_bf16_kernel<<<1024, 256, 0, stream>>>(Wq, Wq_b, 262144);
  cast_bf16_kernel<<<1024, 256, 0, stream>>>(Wk, Wk_b, 262144);
  cast_bf16_kernel<<<1024, 256, 0, stream>>>(Wv, Wv_b, 262144);
  cast_bf16_kernel<<<1024, 256, 0, stream>>>(W1, W1_b, 262144);
  cast_bf16_kernel<<<4096, 256, 0, stream>>>(W2, W2_b, 1048576);
  cast_bf16_kernel<<<4096, 256, 0, stream>>>(W3, W3_b, 1048576);

  // 2. fused QKV: M=8192, N=3072, K=1024  (BM=256, grid 12x32=384)
  gemm8p<256, 2, 2><<<dim3(12 * 32), 512, 0, stream>>>(
      xbf, Wq_b, bq, Qf, bk, Kf, bv, Vbf, 3072, 1024, 0, 0, 0, 0, 12, 32);
  // 3. normalize + transpose
  l2norm_kernel<<<8192, 256, 0, stream>>>(Qf, Qn);
  l2norm_kernel<<<8192, 256, 0, stream>>>(Kf, Kn);
  transpose_kernel<<<dim3(32, 64, 4), dim3(32, 8), 0, stream>>>(Vbf, Vt, 2048, 1024);
  // 4. sim = Qn @ Kn^T per batch (M=N=2048, K=1024; grid 8x8x4=256)
  gemm8p<256, 2, 0><<<dim3(8 * 8 * 4), 512, 0, stream>>>(
      Qn, Kn, nullptr, simf, nullptr, nullptr, nullptr, nullptr,
      2048, 1024, 2097152L, 2097152L, 4194304L, 0, 8, 8);
  // 5. softmax
  softmax_kernel<<<8192, 256, 0, stream>>>(simf, P);
  // 6. attnout = P @ V (M=2048, N=1024, K=2048, per batch; grid 4x16x4=256)
  gemm8p<128, 3, 1><<<dim3(4 * 16 * 4), 512, 0, stream>>>(
      P, Vt, nullptr, attnout, nullptr, nullptr, nullptr, nullptr,
      1024, 2048, 4194304L, 2097152L, 2097152L, 0, 4, 16);
  // 7. MLP
  gemm8p<128, 3, 1><<<dim3(4 * 64), 512, 0, stream>>>(
      attnout, W1_b, b1, h1, nullptr, nullptr, nullptr, nullptr,
      1024, 1024, 0, 0, 0, 1, 4, 64);
  gemm8p<256, 2, 1><<<dim3(16 * 32), 512, 0, stream>>>(
      h1, W2_b, b2, h2, nullptr, nullptr, nullptr, nullptr,
      4096, 1024, 0, 0, 0, 1, 16, 32);
  gemm8p<128, 3, 0><<<dim3(4 * 64), 512, 0, stream>>>(
      h2, W3_b, b3, (float*)d_out, nullptr, nullptr, nullptr, nullptr,
      1024, 4096, 0, 0, 0, 0, 4, 64);
}

// Round 5
// 393.444 us; speedup vs baseline: 1.3666x; 1.0260x over previous
//
#include <hip/hip_runtime.h>

// ---------------------------------------------------------------------------
// Cosine-attention transformer block, MI355X gfx950.  Round 5.
//
// R5 changes vs R4: QKV GEMM -> BM=128/DEPTH=3 with exact-grid 768 (3 full
// rounds, no 75% tail), Q/K/V all written bf16 (was Q,K f32: -32 MB writes);
// l2norm reads bf16; all 7 fp32->bf16 casts fused into one kernel.
//
// GEMM (T1..T5, frag-once): BN=256, BK=64, 512 thr = 8 waves (2M x 4N).
// BM in {128,256}; DEPTH: BM=256 -> 2 (128 KB LDS), BM=128 -> 3 (144 KB).
// XOR swizzle granule^=row&7; global_load_lds w=16 pre-swizzled source.
// Frag-once phases: ph0 read{Ah0,Bh0} mfma q00 | ph1 read{Bh1} q01 |
// ph2 read{Ah1} q10 | ph3 q11.  vmcnt derivation in R4 header (unchanged).
//
// Workspace (168 MiB, lifetime-aliased):
//   [0,  64Mi): Qbf(16)+Kbf(16) -> simf f32(64) -> h2 bf16(64)
//   [64, 96Mi): xbf(16)+Vbf(16) -> P bf16(32)
//   [96,120Mi): weights bf16 (Wq,Wk,Wv,W1 2Mi ea; W2 8Mi; W3 8Mi)
//   [120,168Mi): Qn,Kn,Vt bf16 (16Mi ea); attnout=Qn, h1=Kn after sim
// ---------------------------------------------------------------------------

using u16 = unsigned short;
using bf16x8 = __attribute__((ext_vector_type(8))) __bf16;
using f32x4  = __attribute__((ext_vector_type(4))) float;

__device__ __forceinline__ u16 f2bf(float f) {
  unsigned u = __float_as_uint(f);
  unsigned r = (u + 0x7FFFu + ((u >> 16) & 1u)) >> 16;
  return (u16)r;
}
__device__ __forceinline__ float bf2f(u16 h) {
  return __uint_as_float(((unsigned)h) << 16);
}

// ---------------- fused fp32 -> bf16 cast (7 segments, one launch) ---------
struct CastSegs {
  const float* src[7];
  u16* dst[7];
  long beg[8];  // cumulative n4 boundaries
};
__global__ __launch_bounds__(256) void cast_multi_kernel(CastSegs cs) {
  long idx = (long)blockIdx.x * 256 + threadIdx.x;
  if (idx >= cs.beg[7]) return;
  int seg = 0;
#pragma unroll
  for (int s = 1; s < 7; ++s) seg += (idx >= cs.beg[s]) ? 1 : 0;
  const long loc = idx - cs.beg[seg];
  float4 v = reinterpret_cast<const float4*>(cs.src[seg])[loc];
  ushort4 o;
  o.x = f2bf(v.x); o.y = f2bf(v.y); o.z = f2bf(v.z); o.w = f2bf(v.w);
  reinterpret_cast<ushort4*>(cs.dst[seg])[loc] = o;
}

// ---------------- row L2-normalize: bf16 [rows][1024] -> bf16 ----------------
__global__ __launch_bounds__(256) void l2norm_kernel(
    const u16* __restrict__ in, u16* __restrict__ out) {
  __shared__ float red[4];
  long row = blockIdx.x;
  const int tid = threadIdx.x, lane = tid & 63, wave = tid >> 6;
  ushort4 h = *reinterpret_cast<const ushort4*>(in + row * 1024 + tid * 4);
  float x0 = bf2f(h.x), x1 = bf2f(h.y), x2 = bf2f(h.z), x3 = bf2f(h.w);
  float ss = x0 * x0 + x1 * x1 + x2 * x2 + x3 * x3;
#pragma unroll
  for (int o = 32; o; o >>= 1) ss += __shfl_xor(ss, o);
  if (lane == 0) red[wave] = ss;
  __syncthreads();
  ss = red[0] + red[1] + red[2] + red[3];
  float s = 1.0f / fmaxf(sqrtf(ss), 1e-12f);
  ushort4 o;
  o.x = f2bf(x0 * s); o.y = f2bf(x1 * s); o.z = f2bf(x2 * s); o.w = f2bf(x3 * s);
  *reinterpret_cast<ushort4*>(out + row * 1024 + tid * 4) = o;
}

// ---------------- bf16 transpose: in [rows][cols] -> out [cols][rows] -------
__global__ void transpose_kernel(const u16* __restrict__ in, u16* __restrict__ out,
                                 int rows, int cols) {
  __shared__ u16 t[32][33];
  const int c0 = blockIdx.x * 32, r0 = blockIdx.y * 32;
  const long off = (long)blockIdx.z * rows * cols;
  const u16* ib = in + off;
  u16* ob = out + off;
  const int tx = threadIdx.x, ty = threadIdx.y;  // (32, 8)
#pragma unroll
  for (int j = 0; j < 4; ++j)
    t[ty + j * 8][tx] = ib[(long)(r0 + ty + j * 8) * cols + c0 + tx];
  __syncthreads();
#pragma unroll
  for (int j = 0; j < 4; ++j)
    ob[(long)(c0 + ty + j * 8) * rows + r0 + tx] = t[tx][ty + j * 8];
}

// ---------------- row softmax: f32 [rows][2048] -> bf16 ----------------
__global__ __launch_bounds__(256) void softmax_kernel(
    const float* __restrict__ in, u16* __restrict__ out) {
  __shared__ float red[4];
  long row = blockIdx.x;
  const int tid = threadIdx.x, lane = tid & 63, wave = tid >> 6;
  const float* p = in + row * 2048;
  float v[8];
  float4 a = *reinterpret_cast<const float4*>(p + tid * 8);
  float4 b = *reinterpret_cast<const float4*>(p + tid * 8 + 4);
  v[0] = a.x; v[1] = a.y; v[2] = a.z; v[3] = a.w;
  v[4] = b.x; v[5] = b.y; v[6] = b.z; v[7] = b.w;
  float m = v[0];
#pragma unroll
  for (int i = 1; i < 8; ++i) m = fmaxf(m, v[i]);
#pragma unroll
  for (int o = 32; o; o >>= 1) m = fmaxf(m, __shfl_xor(m, o));
  if (lane == 0) red[wave] = m;
  __syncthreads();
  m = fmaxf(fmaxf(red[0], red[1]), fmaxf(red[2], red[3]));
  float s = 0.0f;
#pragma unroll
  for (int i = 0; i < 8; ++i) { v[i] = __expf(v[i] - m); s += v[i]; }
#pragma unroll
  for (int o = 32; o; o >>= 1) s += __shfl_xor(s, o);
  __syncthreads();
  if (lane == 0) red[wave] = s;
  __syncthreads();
  s = red[0] + red[1] + red[2] + red[3];
  float inv = 1.0f / s;
  ushort4 o0, o1;
  o0.x = f2bf(v[0] * inv); o0.y = f2bf(v[1] * inv);
  o0.z = f2bf(v[2] * inv); o0.w = f2bf(v[3] * inv);
  o1.x = f2bf(v[4] * inv); o1.y = f2bf(v[5] * inv);
  o1.z = f2bf(v[6] * inv); o1.w = f2bf(v[7] * inv);
  *reinterpret_cast<ushort4*>(out + row * 2048 + tid * 8) = o0;
  *reinterpret_cast<ushort4*>(out + row * 2048 + tid * 8 + 4) = o1;
}

// ---------------- 8-phase bf16 NT GEMM (frag-once reads) ----------------
// C[m,n] = sum_k A[m,k]*B[n,k] (+bias[n]) (+relu).
// MODE: 0 = f32 out, 1 = bf16 out, 2 = QKV column-route (all bf16 out):
//   cols [0,1024)->Cout/bias, [1024,2048)->Cout2/bias2, [2048,3072)->Cout3/bias3.
// Launched as 1-D grid of gx*gy*gz blocks, x-major.
template <int BM, int DEPTH, int MODE>
__global__ __launch_bounds__(512, 2) void gemm8p(
    const u16* __restrict__ A, const u16* __restrict__ Bw,
    const float* __restrict__ bias, void* __restrict__ Cout,
    const float* __restrict__ bias2, void* __restrict__ Cout2,
    const float* __restrict__ bias3, void* __restrict__ Cout3,
    int N, int K, long batchA, long batchB, long batchC, int relu,
    int gx, int gy) {
  constexpr int MF  = BM / 32;        // m-frags per wave (8 or 4)
  constexpr int MH  = MF / 2;         // m-frags per half
  constexpr int ASZ = BM * 64;        // u16 per A buffer
  constexpr int BSZ = 256 * 64;
  constexpr int AR  = BM / 64;        // A stage rounds per K-tile (4 or 2)
  __shared__ u16 lds[DEPTH * (ASZ + BSZ)];
  u16* const ldsA = lds;
  u16* const ldsB = lds + DEPTH * ASZ;

  // ---- XCD-bijective block swizzle (m204) ----
  const int nwg = gridDim.x;
  const int lid = blockIdx.x;
  const int q = nwg >> 3, r = nwg & 7;
  const int xcd = lid & 7, jj = lid >> 3;
  const int wg = (xcd < r ? xcd * (q + 1) : r * (q + 1) + (xcd - r) * q) + jj;
  const int bx = wg % gx;
  const int rest = wg / gx;
  const int by = rest % gy;
  const int bz = rest / gy;

  const int tid = threadIdx.x, wave = tid >> 6, lane = tid & 63;
  const int wr = wave >> 2, wc = wave & 3;
  const int fr = lane & 15, hi = lane >> 4;

  const long Abase = bz * batchA + (long)by * BM * K;
  const long Bbase = bz * batchB + (long)bx * 256 * K;

  // ---- precomputed swizzled ds_read offsets (u16 units) ----
  int aoff[MF][2], boff[4][2];
#pragma unroll
  for (int m = 0; m < MF; ++m) {
    const int qm = m / MH, ml = m % MH;
    const int row = qm * (BM / 2) + wr * (BM / 4) + ml * 16 + fr;
#pragma unroll
    for (int ks = 0; ks < 2; ++ks) {
      const int gg = ks * 4 + hi;
      aoff[m][ks] = row * 64 + ((gg ^ (row & 7)) * 8);
    }
  }
#pragma unroll
  for (int n = 0; n < 4; ++n) {
    const int qn = n >> 1, nl = n & 1;
    const int row = qn * 128 + wc * 32 + nl * 16 + fr;
#pragma unroll
    for (int ks = 0; ks < 2; ++ks) {
      const int gg = ks * 4 + hi;
      boff[n][ks] = row * 64 + ((gg ^ (row & 7)) * 8);
    }
  }

  // ---- stage source offsets (pre-swizzled global, m173) ----
  const int rA = wave * 8 + (lane >> 3);
  const int g8 = (((lane & 7) ^ (lane >> 3)) * 8);
  long asrc[AR], bsrc[4];
#pragma unroll
  for (int rr = 0; rr < AR; ++rr) asrc[rr] = Abase + (long)(rr * 64 + rA) * K + g8;
#pragma unroll
  for (int rr = 0; rr < 4; ++rr) bsrc[rr] = Bbase + (long)(rr * 64 + rA) * K + g8;

#define STAGE_A(bufp, rr, k0)                                                  \
  __builtin_amdgcn_global_load_lds(                                            \
      (const __attribute__((address_space(1))) void*)(A + asrc[rr] + (k0)),    \
      (__attribute__((address_space(3))) void*)((bufp) + (rr) * 4096 + wave * 512), \
      16, 0, 0)
#define STAGE_B(bufp, rr, k0)                                                  \
  __builtin_amdgcn_global_load_lds(                                            \
      (const __attribute__((address_space(1))) void*)(Bw + bsrc[rr] + (k0)),   \
      (__attribute__((address_space(3))) void*)((bufp) + (rr) * 4096 + wave * 512), \
      16, 0, 0)

  const int NT = K >> 6;

  // ---- prologue ----
  if constexpr (DEPTH == 2) {
#pragma unroll
    for (int rr = 0; rr < AR; ++rr) STAGE_A(ldsA, rr, 0);
#pragma unroll
    for (int rr = 0; rr < 4; ++rr) STAGE_B(ldsB, rr, 0);
    asm volatile("s_waitcnt vmcnt(0)" ::: "memory");
  } else {
#pragma unroll
    for (int rr = 0; rr < AR; ++rr) STAGE_A(ldsA, rr, 0);
#pragma unroll
    for (int rr = 0; rr < 4; ++rr) STAGE_B(ldsB, rr, 0);
    if (NT > 1) {
#pragma unroll
      for (int rr = 0; rr < AR; ++rr) STAGE_A(ldsA + ASZ, rr, 64);
#pragma unroll
      for (int rr = 0; rr < 4; ++rr) STAGE_B(ldsB + BSZ, rr, 64);
      asm volatile("s_waitcnt vmcnt(6)" ::: "memory");  // L=6: tile 0 landed
    } else {
      asm volatile("s_waitcnt vmcnt(0)" ::: "memory");
    }
  }
  __builtin_amdgcn_s_barrier();

  f32x4 acc[MF][4] = {};

#define READ_AHALF(dst, h)                                                     \
  _Pragma("unroll") for (int mm = 0; mm < MH; ++mm)                            \
  _Pragma("unroll") for (int ks = 0; ks < 2; ++ks)                             \
    dst[mm][ks] = *reinterpret_cast<const bf16x8*>(&curA[aoff[(h) * MH + mm][ks]]);
#define READ_BHALF(dst, h)                                                     \
  _Pragma("unroll") for (int nn = 0; nn < 2; ++nn)                             \
  _Pragma("unroll") for (int ks = 0; ks < 2; ++ks)                             \
    dst[nn][ks] = *reinterpret_cast<const bf16x8*>(&curB[boff[(h) * 2 + nn][ks]]);
#define MFMA_Q(ah, bh, qm, qn)                                                 \
  __builtin_amdgcn_s_setprio(1);                                               \
  _Pragma("unroll") for (int ks = 0; ks < 2; ++ks)                             \
  _Pragma("unroll") for (int mm = 0; mm < MH; ++mm)                            \
  _Pragma("unroll") for (int nn = 0; nn < 2; ++nn)                             \
    acc[(qm) * MH + mm][(qn) * 2 + nn] =                                       \
        __builtin_amdgcn_mfma_f32_16x16x32_bf16(                               \
            ah[mm][ks], bh[nn][ks], acc[(qm) * MH + mm][(qn) * 2 + nn], 0, 0, 0); \
  __builtin_amdgcn_s_setprio(0);

  for (int t = 0; t < NT; ++t) {
    u16* curA = ldsA + (t % DEPTH) * ASZ;
    u16* curB = ldsB + (t % DEPTH) * BSZ;
    const int ts = t + DEPTH - 1;      // tile staged this iteration
    const bool st = ts < NT;
    u16* nxtA = ldsA + (ts % DEPTH) * ASZ;
    u16* nxtB = ldsB + (ts % DEPTH) * BSZ;
    const int k0n = ts << 6;

    bf16x8 a0[MH][2], a1[MH][2], b0[2][2], b1[2][2];

    // ---- ph0: read Ah0,Bh0 ; MFMA q(0,0) ----
    READ_AHALF(a0, 0)
    READ_BHALF(b0, 0)
    if (st) {
#pragma unroll
      for (int rr = 0; rr < AR / 2; ++rr) STAGE_A(nxtA, rr, k0n);
    }
    __builtin_amdgcn_s_barrier();
    MFMA_Q(a0, b0, 0, 0)
    if constexpr (DEPTH == 2) {
      if (st) asm volatile("s_waitcnt vmcnt(2)" ::: "memory");
      else    asm volatile("s_waitcnt vmcnt(0)" ::: "memory");
    }
    __builtin_amdgcn_s_barrier();

    // ---- ph1: read Bh1 ; MFMA q(0,1) ----
    READ_BHALF(b1, 1)
    if (st) {
#pragma unroll
      for (int rr = AR / 2; rr < AR; ++rr) STAGE_A(nxtA, rr, k0n);
    }
    __builtin_amdgcn_s_barrier();
    MFMA_Q(a0, b1, 0, 1)
    __builtin_amdgcn_s_barrier();

    // ---- ph2: read Ah1 ; MFMA q(1,0) ----
    READ_AHALF(a1, 1)
    if (st) { STAGE_B(nxtB, 0, k0n); STAGE_B(nxtB, 1, k0n); }
    __builtin_amdgcn_s_barrier();
    MFMA_Q(a1, b0, 1, 0)
    __builtin_amdgcn_s_barrier();

    // ---- ph3: MFMA q(1,1) ----
    if (st) { STAGE_B(nxtB, 2, k0n); STAGE_B(nxtB, 3, k0n); }
    __builtin_amdgcn_s_barrier();
    MFMA_Q(a1, b1, 1, 1)
    if constexpr (DEPTH == 2) {
      if (st) asm volatile("s_waitcnt vmcnt(2)" ::: "memory");
    } else {
      if (st) asm volatile("s_waitcnt vmcnt(6)" ::: "memory");
      else    asm volatile("s_waitcnt vmcnt(0)" ::: "memory");
    }
    __builtin_amdgcn_s_barrier();
  }
#undef STAGE_A
#undef STAGE_B
#undef READ_AHALF
#undef READ_BHALF
#undef MFMA_Q

  // ---- epilogue ----
  const long cbase = bz * batchC;
  const int crow = by * BM;
  int ccol = bx * 256;
  const float* bp = bias;
  void* cp = Cout;
  bool obf = (MODE == 1) || (MODE == 2);
  int Nst = N;
  if constexpr (MODE == 2) {
    const int sel = ccol >> 10;  // block-uniform
    if (sel == 1) { bp = bias2; cp = Cout2; }
    else if (sel == 2) { bp = bias3; cp = Cout3; }
    ccol &= 1023;
    Nst = 1024;
  }
#pragma unroll
  for (int m = 0; m < MF; ++m) {
    const int qm = m / MH, ml = m % MH;
    const int r0 = crow + qm * (BM / 2) + wr * (BM / 4) + ml * 16 + hi * 4;
#pragma unroll
    for (int n = 0; n < 4; ++n) {
      const int qn = n >> 1, nl = n & 1;
      const int c = ccol + qn * 128 + wc * 32 + nl * 16 + fr;
      const float bb = bp ? bp[c] : 0.0f;
#pragma unroll
      for (int j = 0; j < 4; ++j) {
        float v = acc[m][n][j] + bb;
        if (relu) v = fmaxf(v, 0.0f);
        const long idx = cbase + (long)(r0 + j) * Nst + c;
        if (obf) ((u16*)cp)[idx] = f2bf(v);
        else     ((float*)cp)[idx] = v;
      }
    }
  }
}

// ---------------------------------------------------------------------------
extern "C" void kernel_launch(void* const* d_in, const int* in_sizes, int n_in,
                              void* d_out, int out_size, void* d_ws, size_t ws_size,
                              hipStream_t stream) {
  (void)in_sizes; (void)n_in; (void)out_size; (void)ws_size;
  const float* x  = (const float*)d_in[0];
  const float* Wq = (const float*)d_in[1];
  const float* bq = (const float*)d_in[2];
  const float* Wk = (const float*)d_in[3];
  const float* bk = (const float*)d_in[4];
  const float* Wv = (const float*)d_in[5];
  const float* bv = (const float*)d_in[6];
  const float* W1 = (const float*)d_in[7];
  const float* b1 = (const float*)d_in[8];
  const float* W2 = (const float*)d_in[9];
  const float* b2 = (const float*)d_in[10];
  const float* W3 = (const float*)d_in[11];
  const float* b3 = (const float*)d_in[12];

  char* ws = (char*)d_ws;
  const size_t MB = 1u << 20;
  // region 0
  u16* Qbf  = (u16*)(ws + 0);
  u16* Kbf  = Qbf + 8388608;
  float* simf = (float*)(ws + 0);
  u16*   h2   = (u16*)(ws + 0);
  // region 1
  u16* xbf = (u16*)(ws + 64 * MB);
  u16* Vbf = xbf + (size_t)8192 * 1024;
  u16* P   = (u16*)(ws + 64 * MB);
  // region 2 (weights, persistent)
  u16* Wq_b = (u16*)(ws + 96 * MB);   // Wq,Wk,Wv contiguous -> [3072][1024]
  u16* Wk_b = Wq_b + 1048576;
  u16* Wv_b = Wk_b + 1048576;
  u16* W1_b = Wv_b + 1048576;
  u16* W2_b = W1_b + 1048576;
  u16* W3_b = W2_b + 4194304;
  // region 3
  u16* Qn = (u16*)(ws + 120 * MB);
  u16* Kn = Qn + 8388608;
  u16* Vt = Kn + 8388608;
  u16* attnout = Qn;  // Qn dead after sim GEMM
  u16* h1      = Kn;  // Kn dead after sim GEMM

  // 1. fused casts (x + 6 weights), one launch
  CastSegs cs;
  cs.src[0] = x;  cs.dst[0] = xbf;
  cs.src[1] = Wq; cs.dst[1] = Wq_b;
  cs.src[2] = Wk; cs.dst[2] = Wk_b;
  cs.src[3] = Wv; cs.dst[3] = Wv_b;
  cs.src[4] = W1; cs.dst[4] = W1_b;
  cs.src[5] = W2; cs.dst[5] = W2_b;
  cs.src[6] = W3; cs.dst[6] = W3_b;
  long szs[7] = {2097152, 262144, 262144, 262144, 262144, 1048576, 1048576};
  long acc0 = 0;
  for (int i = 0; i < 7; ++i) { cs.beg[i] = acc0; acc0 += szs[i]; }
  cs.beg[7] = acc0;  // 5242880 n4 units
  cast_multi_kernel<<<dim3((unsigned)((acc0 + 255) / 256)), 256, 0, stream>>>(cs);

  // 2. fused QKV: M=8192, N=3072, K=1024.  BM=128, grid 12x64=768 (3 exact
  //    rounds at 1 block/CU), all outputs bf16.
  gemm8p<128, 3, 2><<<dim3(12 * 64), 512, 0, stream>>>(
      xbf, Wq_b, bq, Qbf, bk, Kbf, bv, Vbf, 3072, 1024, 0, 0, 0, 0, 12, 64);
  // 3. normalize + transpose
  l2norm_kernel<<<8192, 256, 0, stream>>>(Qbf, Qn);
  l2norm_kernel<<<8192, 256, 0, stream>>>(Kbf, Kn);
  transpose_kernel<<<dim3(32, 64, 4), dim3(32, 8), 0, stream>>>(Vbf, Vt, 2048, 1024);
  // 4. sim = Qn @ Kn^T per batch (M=N=2048, K=1024; grid 8x8x4=256)
  gemm8p<256, 2, 0><<<dim3(8 * 8 * 4), 512, 0, stream>>>(
      Qn, Kn, nullptr, simf, nullptr, nullptr, nullptr, nullptr,
      2048, 1024, 2097152L, 2097152L, 4194304L, 0, 8, 8);
  // 5. softmax
  softmax_kernel<<<8192, 256, 0, stream>>>(simf, P);
  // 6. attnout = P @ V (M=2048, N=1024, K=2048, per batch; grid 4x16x4=256)
  gemm8p<128, 3, 1><<<dim3(4 * 16 * 4), 512, 0, stream>>>(
      P, Vt, nullptr, attnout, nullptr, nullptr, nullptr, nullptr,
      1024, 2048, 4194304L, 2097152L, 2097152L, 0, 4, 16);
  // 7. MLP
  gemm8p<128, 3, 1><<<dim3(4 * 64), 512, 0, stream>>>(
      attnout, W1_b, b1, h1, nullptr, nullptr, nullptr, nullptr,
      1024, 1024, 0, 0, 0, 1, 4, 64);
  gemm8p<256, 2, 1><<<dim3(16 * 32), 512, 0, stream>>>(
      h1, W2_b, b2, h2, nullptr, nullptr, nullptr, nullptr,
      4096, 1024, 0, 0, 0, 1, 16, 32);
  gemm8p<128, 3, 0><<<dim3(4 * 64), 512, 0, stream>>>(
      h2, W3_b, b3, (float*)d_out, nullptr, nullptr, nullptr, nullptr,
      1024, 4096, 0, 0, 0, 0, 4, 64);
}

// Round 6
// 386.485 us; speedup vs baseline: 1.3912x; 1.0180x over previous
//
#include <hip/hip_runtime.h>

// ---------------------------------------------------------------------------
// Cosine-attention transformer block, MI355X gfx950.  Round 6.
//
// R6 changes vs R5: BM=128 GEMM K-loop restructured 4 phases -> 2 phases
// (16 MFMA/wave/phase, 4 barriers/K-tile instead of 8) to amortize the
// ~550cyc/phase barrier+latency overhead identified in R5 (MLP3 MfmaUtil 31%,
// phase time 800cyc vs 258cyc MFMA content).  vmcnt invariant UNCHANGED:
// iter t stages tile t+2 (6 loads: A0,A1,B0..B3); end-of-iter vmcnt(6)
// guarantees tile t+1 landed (<=12 outstanding, oldest 6 = tile t+1);
// buffer (t+2)%3 = buffer of tile t-1, fully read before iter t's stage
// issues (end-of-iter-(t-1) barrier).  BM=256 4-phase path untouched.
// Also: two l2norm launches merged into one.
//
// GEMM (T1..T5, frag-once): BN=256, BK=64, 512 thr = 8 waves (2M x 4N).
// BM in {128,256}; DEPTH: BM=256 -> 2 (128 KB LDS), BM=128 -> 3 (144 KB).
// XOR swizzle granule^=row&7; global_load_lds w=16 pre-swizzled source.
// ---------------------------------------------------------------------------

using u16 = unsigned short;
using bf16x8 = __attribute__((ext_vector_type(8))) __bf16;
using f32x4  = __attribute__((ext_vector_type(4))) float;

__device__ __forceinline__ u16 f2bf(float f) {
  unsigned u = __float_as_uint(f);
  unsigned r = (u + 0x7FFFu + ((u >> 16) & 1u)) >> 16;
  return (u16)r;
}
__device__ __forceinline__ float bf2f(u16 h) {
  return __uint_as_float(((unsigned)h) << 16);
}

// ---------------- fused fp32 -> bf16 cast (7 segments, one launch) ---------
struct CastSegs {
  const float* src[7];
  u16* dst[7];
  long beg[8];  // cumulative n4 boundaries
};
__global__ __launch_bounds__(256) void cast_multi_kernel(CastSegs cs) {
  long idx = (long)blockIdx.x * 256 + threadIdx.x;
  if (idx >= cs.beg[7]) return;
  int seg = 0;
#pragma unroll
  for (int s = 1; s < 7; ++s) seg += (idx >= cs.beg[s]) ? 1 : 0;
  const long loc = idx - cs.beg[seg];
  float4 v = reinterpret_cast<const float4*>(cs.src[seg])[loc];
  ushort4 o;
  o.x = f2bf(v.x); o.y = f2bf(v.y); o.z = f2bf(v.z); o.w = f2bf(v.w);
  reinterpret_cast<ushort4*>(cs.dst[seg])[loc] = o;
}

// ------- merged row L2-normalize: Q and K bf16 [8192][1024] -> bf16 --------
__global__ __launch_bounds__(256) void l2norm2_kernel(
    const u16* __restrict__ Qi, const u16* __restrict__ Ki,
    u16* __restrict__ Qo, u16* __restrict__ Ko) {
  __shared__ float red[4];
  long row = blockIdx.x;
  const u16* in;
  u16* out;
  if (row < 8192) { in = Qi + row * 1024; out = Qo + row * 1024; }
  else            { in = Ki + (row - 8192) * 1024; out = Ko + (row - 8192) * 1024; }
  const int tid = threadIdx.x, lane = tid & 63, wave = tid >> 6;
  ushort4 h = *reinterpret_cast<const ushort4*>(in + tid * 4);
  float x0 = bf2f(h.x), x1 = bf2f(h.y), x2 = bf2f(h.z), x3 = bf2f(h.w);
  float ss = x0 * x0 + x1 * x1 + x2 * x2 + x3 * x3;
#pragma unroll
  for (int o = 32; o; o >>= 1) ss += __shfl_xor(ss, o);
  if (lane == 0) red[wave] = ss;
  __syncthreads();
  ss = red[0] + red[1] + red[2] + red[3];
  float s = 1.0f / fmaxf(sqrtf(ss), 1e-12f);
  ushort4 o;
  o.x = f2bf(x0 * s); o.y = f2bf(x1 * s); o.z = f2bf(x2 * s); o.w = f2bf(x3 * s);
  *reinterpret_cast<ushort4*>(out + tid * 4) = o;
}

// ---------------- bf16 transpose: in [rows][cols] -> out [cols][rows] -------
__global__ void transpose_kernel(const u16* __restrict__ in, u16* __restrict__ out,
                                 int rows, int cols) {
  __shared__ u16 t[32][33];
  const int c0 = blockIdx.x * 32, r0 = blockIdx.y * 32;
  const long off = (long)blockIdx.z * rows * cols;
  const u16* ib = in + off;
  u16* ob = out + off;
  const int tx = threadIdx.x, ty = threadIdx.y;  // (32, 8)
#pragma unroll
  for (int j = 0; j < 4; ++j)
    t[ty + j * 8][tx] = ib[(long)(r0 + ty + j * 8) * cols + c0 + tx];
  __syncthreads();
#pragma unroll
  for (int j = 0; j < 4; ++j)
    ob[(long)(c0 + ty + j * 8) * rows + r0 + tx] = t[tx][ty + j * 8];
}

// ---------------- row softmax: f32 [rows][2048] -> bf16 ----------------
__global__ __launch_bounds__(256) void softmax_kernel(
    const float* __restrict__ in, u16* __restrict__ out) {
  __shared__ float red[4];
  long row = blockIdx.x;
  const int tid = threadIdx.x, lane = tid & 63, wave = tid >> 6;
  const float* p = in + row * 2048;
  float v[8];
  float4 a = *reinterpret_cast<const float4*>(p + tid * 8);
  float4 b = *reinterpret_cast<const float4*>(p + tid * 8 + 4);
  v[0] = a.x; v[1] = a.y; v[2] = a.z; v[3] = a.w;
  v[4] = b.x; v[5] = b.y; v[6] = b.z; v[7] = b.w;
  float m = v[0];
#pragma unroll
  for (int i = 1; i < 8; ++i) m = fmaxf(m, v[i]);
#pragma unroll
  for (int o = 32; o; o >>= 1) m = fmaxf(m, __shfl_xor(m, o));
  if (lane == 0) red[wave] = m;
  __syncthreads();
  m = fmaxf(fmaxf(red[0], red[1]), fmaxf(red[2], red[3]));
  float s = 0.0f;
#pragma unroll
  for (int i = 0; i < 8; ++i) { v[i] = __expf(v[i] - m); s += v[i]; }
#pragma unroll
  for (int o = 32; o; o >>= 1) s += __shfl_xor(s, o);
  __syncthreads();
  if (lane == 0) red[wave] = s;
  __syncthreads();
  s = red[0] + red[1] + red[2] + red[3];
  float inv = 1.0f / s;
  ushort4 o0, o1;
  o0.x = f2bf(v[0] * inv); o0.y = f2bf(v[1] * inv);
  o0.z = f2bf(v[2] * inv); o0.w = f2bf(v[3] * inv);
  o1.x = f2bf(v[4] * inv); o1.y = f2bf(v[5] * inv);
  o1.z = f2bf(v[6] * inv); o1.w = f2bf(v[7] * inv);
  *reinterpret_cast<ushort4*>(out + row * 2048 + tid * 8) = o0;
  *reinterpret_cast<ushort4*>(out + row * 2048 + tid * 8 + 4) = o1;
}

// ---------------- 8-phase bf16 NT GEMM (frag-once reads) ----------------
// C[m,n] = sum_k A[m,k]*B[n,k] (+bias[n]) (+relu).
// MODE: 0 = f32 out, 1 = bf16 out, 2 = QKV column-route (all bf16 out).
// Launched as 1-D grid of gx*gy*gz blocks, x-major.
template <int BM, int DEPTH, int MODE>
__global__ __launch_bounds__(512, 2) void gemm8p(
    const u16* __restrict__ A, const u16* __restrict__ Bw,
    const float* __restrict__ bias, void* __restrict__ Cout,
    const float* __restrict__ bias2, void* __restrict__ Cout2,
    const float* __restrict__ bias3, void* __restrict__ Cout3,
    int N, int K, long batchA, long batchB, long batchC, int relu,
    int gx, int gy) {
  constexpr int MF  = BM / 32;        // m-frags per wave (8 or 4)
  constexpr int MH  = MF / 2;         // m-frags per half
  constexpr int ASZ = BM * 64;        // u16 per A buffer
  constexpr int BSZ = 256 * 64;
  constexpr int AR  = BM / 64;        // A stage rounds per K-tile (4 or 2)
  __shared__ u16 lds[DEPTH * (ASZ + BSZ)];
  u16* const ldsA = lds;
  u16* const ldsB = lds + DEPTH * ASZ;

  // ---- XCD-bijective block swizzle (m204) ----
  const int nwg = gridDim.x;
  const int lid = blockIdx.x;
  const int q = nwg >> 3, r = nwg & 7;
  const int xcd = lid & 7, jj = lid >> 3;
  const int wg = (xcd < r ? xcd * (q + 1) : r * (q + 1) + (xcd - r) * q) + jj;
  const int bx = wg % gx;
  const int rest = wg / gx;
  const int by = rest % gy;
  const int bz = rest / gy;

  const int tid = threadIdx.x, wave = tid >> 6, lane = tid & 63;
  const int wr = wave >> 2, wc = wave & 3;
  const int fr = lane & 15, hi = lane >> 4;

  const long Abase = bz * batchA + (long)by * BM * K;
  const long Bbase = bz * batchB + (long)bx * 256 * K;

  // ---- precomputed swizzled ds_read offsets (u16 units) ----
  int aoff[MF][2], boff[4][2];
#pragma unroll
  for (int m = 0; m < MF; ++m) {
    const int qm = m / MH, ml = m % MH;
    const int row = qm * (BM / 2) + wr * (BM / 4) + ml * 16 + fr;
#pragma unroll
    for (int ks = 0; ks < 2; ++ks) {
      const int gg = ks * 4 + hi;
      aoff[m][ks] = row * 64 + ((gg ^ (row & 7)) * 8);
    }
  }
#pragma unroll
  for (int n = 0; n < 4; ++n) {
    const int qn = n >> 1, nl = n & 1;
    const int row = qn * 128 + wc * 32 + nl * 16 + fr;
#pragma unroll
    for (int ks = 0; ks < 2; ++ks) {
      const int gg = ks * 4 + hi;
      boff[n][ks] = row * 64 + ((gg ^ (row & 7)) * 8);
    }
  }

  // ---- stage source offsets (pre-swizzled global, m173) ----
  const int rA = wave * 8 + (lane >> 3);
  const int g8 = (((lane & 7) ^ (lane >> 3)) * 8);
  long asrc[AR], bsrc[4];
#pragma unroll
  for (int rr = 0; rr < AR; ++rr) asrc[rr] = Abase + (long)(rr * 64 + rA) * K + g8;
#pragma unroll
  for (int rr = 0; rr < 4; ++rr) bsrc[rr] = Bbase + (long)(rr * 64 + rA) * K + g8;

#define STAGE_A(bufp, rr, k0)                                                  \
  __builtin_amdgcn_global_load_lds(                                            \
      (const __attribute__((address_space(1))) void*)(A + asrc[rr] + (k0)),    \
      (__attribute__((address_space(3))) void*)((bufp) + (rr) * 4096 + wave * 512), \
      16, 0, 0)
#define STAGE_B(bufp, rr, k0)                                                  \
  __builtin_amdgcn_global_load_lds(                                            \
      (const __attribute__((address_space(1))) void*)(Bw + bsrc[rr] + (k0)),   \
      (__attribute__((address_space(3))) void*)((bufp) + (rr) * 4096 + wave * 512), \
      16, 0, 0)

  const int NT = K >> 6;

  // ---- prologue ----
  if constexpr (DEPTH == 2) {
#pragma unroll
    for (int rr = 0; rr < AR; ++rr) STAGE_A(ldsA, rr, 0);
#pragma unroll
    for (int rr = 0; rr < 4; ++rr) STAGE_B(ldsB, rr, 0);
    asm volatile("s_waitcnt vmcnt(0)" ::: "memory");
  } else {
#pragma unroll
    for (int rr = 0; rr < AR; ++rr) STAGE_A(ldsA, rr, 0);
#pragma unroll
    for (int rr = 0; rr < 4; ++rr) STAGE_B(ldsB, rr, 0);
    if (NT > 1) {
#pragma unroll
      for (int rr = 0; rr < AR; ++rr) STAGE_A(ldsA + ASZ, rr, 64);
#pragma unroll
      for (int rr = 0; rr < 4; ++rr) STAGE_B(ldsB + BSZ, rr, 64);
      asm volatile("s_waitcnt vmcnt(6)" ::: "memory");  // L=6: tile 0 landed
    } else {
      asm volatile("s_waitcnt vmcnt(0)" ::: "memory");
    }
  }
  __builtin_amdgcn_s_barrier();

  f32x4 acc[MF][4] = {};

#define READ_AHALF(dst, h)                                                     \
  _Pragma("unroll") for (int mm = 0; mm < MH; ++mm)                            \
  _Pragma("unroll") for (int ks = 0; ks < 2; ++ks)                             \
    dst[mm][ks] = *reinterpret_cast<const bf16x8*>(&curA[aoff[(h) * MH + mm][ks]]);
#define READ_BHALF(dst, h)                                                     \
  _Pragma("unroll") for (int nn = 0; nn < 2; ++nn)                             \
  _Pragma("unroll") for (int ks = 0; ks < 2; ++ks)                             \
    dst[nn][ks] = *reinterpret_cast<const bf16x8*>(&curB[boff[(h) * 2 + nn][ks]]);
#define MFMA_Q(ah, bh, qm, qn)                                                 \
  _Pragma("unroll") for (int ks = 0; ks < 2; ++ks)                             \
  _Pragma("unroll") for (int mm = 0; mm < MH; ++mm)                            \
  _Pragma("unroll") for (int nn = 0; nn < 2; ++nn)                             \
    acc[(qm) * MH + mm][(qn) * 2 + nn] =                                       \
        __builtin_amdgcn_mfma_f32_16x16x32_bf16(                               \
            ah[mm][ks], bh[nn][ks], acc[(qm) * MH + mm][(qn) * 2 + nn], 0, 0, 0);

  for (int t = 0; t < NT; ++t) {
    u16* curA = ldsA + (t % DEPTH) * ASZ;
    u16* curB = ldsB + (t % DEPTH) * BSZ;
    const int ts = t + DEPTH - 1;      // tile staged this iteration
    const bool st = ts < NT;
    u16* nxtA = ldsA + (ts % DEPTH) * ASZ;
    u16* nxtB = ldsB + (ts % DEPTH) * BSZ;
    const int k0n = ts << 6;

    bf16x8 a0[MH][2], a1[MH][2], b0[2][2], b1[2][2];

    if constexpr (BM == 128) {
      // ---- 2-phase body: 16 MFMA/wave/phase, 4 barriers/K-tile ----
      // phase A: read Ah0,Bh0,Bh1 ; MFMA q(0,0),q(0,1) ; stage A(t+2)
      READ_AHALF(a0, 0)
      READ_BHALF(b0, 0)
      READ_BHALF(b1, 1)
      if (st) { STAGE_A(nxtA, 0, k0n); STAGE_A(nxtA, 1, k0n); }
      __builtin_amdgcn_s_barrier();
      __builtin_amdgcn_s_setprio(1);
      MFMA_Q(a0, b0, 0, 0)
      MFMA_Q(a0, b1, 0, 1)
      __builtin_amdgcn_s_setprio(0);
      __builtin_amdgcn_s_barrier();
      // phase B: read Ah1 ; MFMA q(1,0),q(1,1) ; stage B(t+2) ; vmcnt
      READ_AHALF(a1, 1)
      if (st) {
        STAGE_B(nxtB, 0, k0n); STAGE_B(nxtB, 1, k0n);
        STAGE_B(nxtB, 2, k0n); STAGE_B(nxtB, 3, k0n);
      }
      __builtin_amdgcn_s_barrier();
      __builtin_amdgcn_s_setprio(1);
      MFMA_Q(a1, b0, 1, 0)
      MFMA_Q(a1, b1, 1, 1)
      __builtin_amdgcn_s_setprio(0);
      if (st) asm volatile("s_waitcnt vmcnt(6)" ::: "memory");
      else    asm volatile("s_waitcnt vmcnt(0)" ::: "memory");
      __builtin_amdgcn_s_barrier();
    } else {
      // ---- 4-phase body (BM=256, DEPTH=2), unchanged from R4 ----
      // ph0: read Ah0,Bh0 ; MFMA q(0,0)
      READ_AHALF(a0, 0)
      READ_BHALF(b0, 0)
      if (st) {
#pragma unroll
        for (int rr = 0; rr < AR / 2; ++rr) STAGE_A(nxtA, rr, k0n);
      }
      __builtin_amdgcn_s_barrier();
      __builtin_amdgcn_s_setprio(1);
      MFMA_Q(a0, b0, 0, 0)
      __builtin_amdgcn_s_setprio(0);
      if (st) asm volatile("s_waitcnt vmcnt(2)" ::: "memory");
      else    asm volatile("s_waitcnt vmcnt(0)" ::: "memory");
      __builtin_amdgcn_s_barrier();
      // ph1: read Bh1 ; MFMA q(0,1)
      READ_BHALF(b1, 1)
      if (st) {
#pragma unroll
        for (int rr = AR / 2; rr < AR; ++rr) STAGE_A(nxtA, rr, k0n);
      }
      __builtin_amdgcn_s_barrier();
      __builtin_amdgcn_s_setprio(1);
      MFMA_Q(a0, b1, 0, 1)
      __builtin_amdgcn_s_setprio(0);
      __builtin_amdgcn_s_barrier();
      // ph2: read Ah1 ; MFMA q(1,0)
      READ_AHALF(a1, 1)
      if (st) { STAGE_B(nxtB, 0, k0n); STAGE_B(nxtB, 1, k0n); }
      __builtin_amdgcn_s_barrier();
      __builtin_amdgcn_s_setprio(1);
      MFMA_Q(a1, b0, 1, 0)
      __builtin_amdgcn_s_setprio(0);
      __builtin_amdgcn_s_barrier();
      // ph3: MFMA q(1,1)
      if (st) { STAGE_B(nxtB, 2, k0n); STAGE_B(nxtB, 3, k0n); }
      __builtin_amdgcn_s_barrier();
      __builtin_amdgcn_s_setprio(1);
      MFMA_Q(a1, b1, 1, 1)
      __builtin_amdgcn_s_setprio(0);
      if (st) asm volatile("s_waitcnt vmcnt(2)" ::: "memory");
      __builtin_amdgcn_s_barrier();
    }
  }
#undef STAGE_A
#undef STAGE_B
#undef READ_AHALF
#undef READ_BHALF
#undef MFMA_Q

  // ---- epilogue ----
  const long cbase = bz * batchC;
  const int crow = by * BM;
  int ccol = bx * 256;
  const float* bp = bias;
  void* cp = Cout;
  bool obf = (MODE == 1) || (MODE == 2);
  int Nst = N;
  if constexpr (MODE == 2) {
    const int sel = ccol >> 10;  // block-uniform
    if (sel == 1) { bp = bias2; cp = Cout2; }
    else if (sel == 2) { bp = bias3; cp = Cout3; }
    ccol &= 1023;
    Nst = 1024;
  }
#pragma unroll
  for (int m = 0; m < MF; ++m) {
    const int qm = m / MH, ml = m % MH;
    const int r0 = crow + qm * (BM / 2) + wr * (BM / 4) + ml * 16 + hi * 4;
#pragma unroll
    for (int n = 0; n < 4; ++n) {
      const int qn = n >> 1, nl = n & 1;
      const int c = ccol + qn * 128 + wc * 32 + nl * 16 + fr;
      const float bb = bp ? bp[c] : 0.0f;
#pragma unroll
      for (int j = 0; j < 4; ++j) {
        float v = acc[m][n][j] + bb;
        if (relu) v = fmaxf(v, 0.0f);
        const long idx = cbase + (long)(r0 + j) * Nst + c;
        if (obf) ((u16*)cp)[idx] = f2bf(v);
        else     ((float*)cp)[idx] = v;
      }
    }
  }
}

// ---------------------------------------------------------------------------
extern "C" void kernel_launch(void* const* d_in, const int* in_sizes, int n_in,
                              void* d_out, int out_size, void* d_ws, size_t ws_size,
                              hipStream_t stream) {
  (void)in_sizes; (void)n_in; (void)out_size; (void)ws_size;
  const float* x  = (const float*)d_in[0];
  const float* Wq = (const float*)d_in[1];
  const float* bq = (const float*)d_in[2];
  const float* Wk = (const float*)d_in[3];
  const float* bk = (const float*)d_in[4];
  const float* Wv = (const float*)d_in[5];
  const float* bv = (const float*)d_in[6];
  const float* W1 = (const float*)d_in[7];
  const float* b1 = (const float*)d_in[8];
  const float* W2 = (const float*)d_in[9];
  const float* b2 = (const float*)d_in[10];
  const float* W3 = (const float*)d_in[11];
  const float* b3 = (const float*)d_in[12];

  char* ws = (char*)d_ws;
  const size_t MB = 1u << 20;
  // region 0
  u16* Qbf  = (u16*)(ws + 0);
  u16* Kbf  = Qbf + 8388608;
  float* simf = (float*)(ws + 0);
  u16*   h2   = (u16*)(ws + 0);
  // region 1
  u16* xbf = (u16*)(ws + 64 * MB);
  u16* Vbf = xbf + (size_t)8192 * 1024;
  u16* P   = (u16*)(ws + 64 * MB);
  // region 2 (weights, persistent)
  u16* Wq_b = (u16*)(ws + 96 * MB);   // Wq,Wk,Wv contiguous -> [3072][1024]
  u16* Wk_b = Wq_b + 1048576;
  u16* Wv_b = Wk_b + 1048576;
  u16* W1_b = Wv_b + 1048576;
  u16* W2_b = W1_b + 1048576;
  u16* W3_b = W2_b + 4194304;
  // region 3
  u16* Qn = (u16*)(ws + 120 * MB);
  u16* Kn = Qn + 8388608;
  u16* Vt = Kn + 8388608;
  u16* attnout = Qn;  // Qn dead after sim GEMM
  u16* h1      = Kn;  // Kn dead after sim GEMM

  // 1. fused casts (x + 6 weights), one launch
  CastSegs cs;
  cs.src[0] = x;  cs.dst[0] = xbf;
  cs.src[1] = Wq; cs.dst[1] = Wq_b;
  cs.src[2] = Wk; cs.dst[2] = Wk_b;
  cs.src[3] = Wv; cs.dst[3] = Wv_b;
  cs.src[4] = W1; cs.dst[4] = W1_b;
  cs.src[5] = W2; cs.dst[5] = W2_b;
  cs.src[6] = W3; cs.dst[6] = W3_b;
  long szs[7] = {2097152, 262144, 262144, 262144, 262144, 1048576, 1048576};
  long acc0 = 0;
  for (int i = 0; i < 7; ++i) { cs.beg[i] = acc0; acc0 += szs[i]; }
  cs.beg[7] = acc0;  // 5242880 n4 units
  cast_multi_kernel<<<dim3((unsigned)((acc0 + 255) / 256)), 256, 0, stream>>>(cs);

  // 2. fused QKV: M=8192, N=3072, K=1024.  BM=128, grid 12x64=768 (3 exact
  //    rounds at 1 block/CU), all outputs bf16.
  gemm8p<128, 3, 2><<<dim3(12 * 64), 512, 0, stream>>>(
      xbf, Wq_b, bq, Qbf, bk, Kbf, bv, Vbf, 3072, 1024, 0, 0, 0, 0, 12, 64);
  // 3. normalize (one launch) + transpose
  l2norm2_kernel<<<16384, 256, 0, stream>>>(Qbf, Kbf, Qn, Kn);
  transpose_kernel<<<dim3(32, 64, 4), dim3(32, 8), 0, stream>>>(Vbf, Vt, 2048, 1024);
  // 4. sim = Qn @ Kn^T per batch (M=N=2048, K=1024; grid 8x8x4=256)
  gemm8p<256, 2, 0><<<dim3(8 * 8 * 4), 512, 0, stream>>>(
      Qn, Kn, nullptr, simf, nullptr, nullptr, nullptr, nullptr,
      2048, 1024, 2097152L, 2097152L, 4194304L, 0, 8, 8);
  // 5. softmax
  softmax_kernel<<<8192, 256, 0, stream>>>(simf, P);
  // 6. attnout = P @ V (M=2048, N=1024, K=2048, per batch; grid 4x16x4=256)
  gemm8p<128, 3, 1><<<dim3(4 * 16 * 4), 512, 0, stream>>>(
      P, Vt, nullptr, attnout, nullptr, nullptr, nullptr, nullptr,
      1024, 2048, 4194304L, 2097152L, 2097152L, 0, 4, 16);
  // 7. MLP
  gemm8p<128, 3, 1><<<dim3(4 * 64), 512, 0, stream>>>(
      attnout, W1_b, b1, h1, nullptr, nullptr, nullptr, nullptr,
      1024, 1024, 0, 0, 0, 1, 4, 64);
  gemm8p<256, 2, 1><<<dim3(16 * 32), 512, 0, stream>>>(
      h1, W2_b, b2, h2, nullptr, nullptr, nullptr, nullptr,
      4096, 1024, 0, 0, 0, 1, 16, 32);
  gemm8p<128, 3, 0><<<dim3(4 * 64), 512, 0, stream>>>(
      h2, W3_b, b3, (float*)d_out, nullptr, nullptr, nullptr, nullptr,
      1024, 4096, 0, 0, 0, 0, 4, 64);
}